// Round 7
// baseline (1083.717 us; speedup 1.0000x reference)
//
#include <hip/hip_runtime.h>
#include <math.h>

#define T_TOK 2056
#define TP 2176      // 17*128  M-padded rows
#define TK 2112      // 33*64   KV-padded rows
#define HIDDEN 512
#define NHEAD 8
#define ADIM 64
#define FFDIM 2048
#define NLAYER 6
#define NORIG 520
#define NOBJ 8
#define NSPLIT 4     // GEMM K-splits
#define FSPLIT 4     // flash KV splits

typedef float f32x4 __attribute__((ext_vector_type(4)));
typedef __attribute__((__ext_vector_type__(8))) __bf16 bf16x8;

#if __has_builtin(__builtin_amdgcn_exp2f)
#define EXP2(x) __builtin_amdgcn_exp2f(x)
#else
#define EXP2(x) exp2f(x)
#endif

__device__ __forceinline__ unsigned short f2bf(float f) {
  unsigned int u = __float_as_uint(f);
  u += 0x7FFFu + ((u >> 16) & 1u);
  return (unsigned short)(u >> 16);
}
__device__ __forceinline__ float bf2f(unsigned short u) {
  return __uint_as_float(((unsigned int)u) << 16);
}
// packed f32x2 -> bf16x2 (lo = a, hi = b); HW single-op on gfx950
__device__ __forceinline__ unsigned pk2bf(float a, float b) {
#if __has_builtin(__builtin_amdgcn_cvt_pk_bf16_f32)
  auto v = __builtin_amdgcn_cvt_pk_bf16_f32(a, b);
  unsigned u;
  __builtin_memcpy(&u, &v, 4);
  return u;
#else
  return (unsigned)f2bf(a) | ((unsigned)f2bf(b) << 16);
#endif
}

// ---------------- block reduction helpers (256 threads = 4 waves) ----------------

__device__ inline float blockReduceSum(float v, float* sb) {
#pragma unroll
  for (int off = 32; off > 0; off >>= 1) v += __shfl_down(v, off, 64);
  int wid = threadIdx.x >> 6;
  __syncthreads();
  if ((threadIdx.x & 63) == 0) sb[wid] = v;
  __syncthreads();
  return sb[0] + sb[1] + sb[2] + sb[3];
}

// ---------------- token embedding: project + LN + leaky_relu (fp32 + bf16 mirror) ----

__global__ __launch_bounds__(256) void embed_kernel(
    const float* __restrict__ obj, const float* __restrict__ st0,
    const float* __restrict__ Wpg, const float* __restrict__ bpg,
    const float* __restrict__ pg_g, const float* __restrict__ pg_b,
    const float* __restrict__ Wps, const float* __restrict__ bps,
    const float* __restrict__ ps_g, const float* __restrict__ ps_b,
    float* __restrict__ x, unsigned short* __restrict__ xb)
{
  __shared__ float sb[4];
  int t = blockIdx.x;
  int j0 = threadIdx.x, j1 = threadIdx.x + 256;
  float a0, a1;
  const float *g, *b;
  if (t < NOBJ) {
    a0 = bpg[j0]; a1 = bpg[j1];
    const float* in = obj + t * 100;
    for (int i = 0; i < 100; i++) {
      float w = in[i];
      a0 += w * Wpg[i * HIDDEN + j0];
      a1 += w * Wpg[i * HIDDEN + j1];
    }
    g = pg_g; b = pg_b;
  } else {
    int tt = t - NOBJ, s = tt >> 2, p = tt & 3;
    float c0 = st0[s * 10 + p * 2], c1 = st0[s * 10 + p * 2 + 1];
    a0 = bps[j0] + c0 * Wps[j0] + c1 * Wps[HIDDEN + j0];
    a1 = bps[j1] + c0 * Wps[j1] + c1 * Wps[HIDDEN + j1];
    g = ps_g; b = ps_b;
  }
  float s1 = blockReduceSum(a0 + a1, sb);
  float s2 = blockReduceSum(a0 * a0 + a1 * a1, sb);
  float m = s1 * (1.0f / HIDDEN);
  float var = s2 * (1.0f / HIDDEN) - m * m;
  float inv = rsqrtf(var + 1e-5f);
  float y0 = (a0 - m) * inv * g[j0] + b[j0];
  float y1 = (a1 - m) * inv * g[j1] + b[j1];
  y0 = y0 >= 0.f ? y0 : 0.01f * y0;
  y1 = y1 >= 0.f ? y1 : 0.01f * y1;
  x[t * HIDDEN + j0] = y0;
  x[t * HIDDEN + j1] = y1;
  xb[t * HIDDEN + j0] = f2bf(y0);
  xb[t * HIDDEN + j1] = f2bf(y1);
}

// zero xb pad rows (re-run every launch; ws is re-poisoned)
__global__ __launch_bounds__(256) void padzero(unsigned short* __restrict__ xb) {
  int i = blockIdx.x * 256 + threadIdx.x;
  if (i < (TP - T_TOK) * HIDDEN) xb[T_TOK * HIDDEN + i] = 0;
}

// ---------------- precompute rel-pos bias table: posb[h][520][520] (bf16) ----------
// posb = ((emb_a[rpe_a]+emb_d[rpe_d]) * 0.125 + mask) * log2(e)   (layer-invariant)

__global__ __launch_bounds__(256) void posbuild(
    const int* __restrict__ rpe_a, const int* __restrict__ rpe_d,
    const float* __restrict__ emb_a, const float* __restrict__ emb_d,
    const float* __restrict__ mask, unsigned short* __restrict__ posb)
{
  int i = blockIdx.x;
  for (int j = threadIdx.x; j < NORIG; j += 256) {
    int a = rpe_a[i * NORIG + j];
    int d = rpe_d[i * NORIG + j];
    float mk = mask[i * NORIG + j];
#pragma unroll
    for (int h = 0; h < NHEAD; h++) {
      float v = ((emb_a[a * NHEAD + h] + emb_d[d * NHEAD + h]) * 0.125f + mk) * 1.44269504f;
      posb[(h * NORIG + i) * NORIG + j] = f2bf(v);
    }
  }
}

// ---------------- weight transpose+convert: fp32 [K][N] -> bf16 [N][K] ----------------

__global__ __launch_bounds__(256) void wtrans(
    const float* __restrict__ Wq, const float* __restrict__ Wk, const float* __restrict__ Wv,
    const float* __restrict__ Wo, const float* __restrict__ W1, const float* __restrict__ W2,
    unsigned short* __restrict__ Wqkvt, unsigned short* __restrict__ Wot,
    unsigned short* __restrict__ W1t, unsigned short* __restrict__ W2t)
{
  __shared__ float t[64 * 65];
  int b = blockIdx.x;
  const float* src; unsigned short* dst; int N, K, tk, tn;
  if (b < 192) {
    int m = b >> 6, bb = b & 63;
    src = m == 0 ? Wq : m == 1 ? Wk : Wv;
    dst = Wqkvt + m * 512 * 512;
    K = 512; N = 512; tk = bb & 7; tn = bb >> 3;
  } else if (b < 256) {
    int bb = b - 192; src = Wo; dst = Wot; K = 512; N = 512; tk = bb & 7; tn = bb >> 3;
  } else if (b < 512) {
    int bb = b - 256; src = W1; dst = W1t; K = 512; N = 2048; tk = bb & 7; tn = bb >> 3;
  } else {
    int bb = b - 512; src = W2; dst = W2t; K = 2048; N = 512; tk = bb & 31; tn = bb >> 5;
  }
  int k0 = tk * 64, n0 = tn * 64;
  int tid = threadIdx.x;
  int r = tid >> 2, c0 = (tid & 3) * 16;
  const float* sp = src + (k0 + r) * N + n0 + c0;
#pragma unroll
  for (int q = 0; q < 4; q++) {
    float4 f = *(const float4*)(sp + q * 4);
    t[r * 65 + c0 + q * 4 + 0] = f.x;
    t[r * 65 + c0 + q * 4 + 1] = f.y;
    t[r * 65 + c0 + q * 4 + 2] = f.z;
    t[r * 65 + c0 + q * 4 + 3] = f.w;
  }
  __syncthreads();
  unsigned short vals[16];
#pragma unroll
  for (int j = 0; j < 16; j++) vals[j] = f2bf(t[(c0 + j) * 65 + r]);
  unsigned short* dp = dst + (n0 + r) * K + k0 + c0;
  *(int4*)dp = *(int4*)&vals[0];
  *(int4*)(dp + 8) = *(int4*)&vals[8];
}

// ---------------- MFMA GEMM: C[M=2176][N] = A[.][K] * Bt[N][K]^T, bf16 in / fp32 acc ----
// BM=64, BN=128, BK=32; 4 waves each 32x64. Double-buffered LDS, 1 barrier per k-iter,
// depth-2.5 register prefetch (loads issued ~2 iters before their LDS store-wait).
// mode 0: +bias(seg) -> scatter bf16 to qh/kh/vh [head][TP][64]; Q scaled 0.125*log2e
// mode 1: split-K partial -> fp32 df[z][TP][ldc] (NO bias)
// mode 2: +bias, leaky -> bf16 d0

__global__ __launch_bounds__(256) void gemm_bt(
    const unsigned short* __restrict__ A, int lda,
    const unsigned short* __restrict__ Bt, int ldb, int K, int mode,
    const float* __restrict__ b0, const float* __restrict__ b1, const float* __restrict__ b2,
    unsigned short* __restrict__ d0, unsigned short* __restrict__ d1, unsigned short* __restrict__ d2,
    float* __restrict__ df, int ldc)
{
  __shared__ unsigned short As[2][64 * 40];
  __shared__ unsigned short Bs[2][128 * 40];
  const int tid = threadIdx.x;
  const int lane = tid & 63, wave = tid >> 6;
  const int l15 = lane & 15, quad = lane >> 4;
  const int rowBase = blockIdx.y * 64, colBase = blockIdx.x * 128;
  const int mw = (wave & 1) * 32, nw = (wave >> 1) * 64;
  const int sr = tid >> 2, sc = (tid & 3) * 8;
  const int zz = blockIdx.z;
  const int kLen = K / gridDim.z;
  const int kb0 = zz * kLen;
  const int nIter = kLen >> 5;           // 4 or 16 — always even, >= 4
  const unsigned short* Ag0 = A + (rowBase + sr) * lda + sc;
  const unsigned short* Bg0 = Bt + (colBase + sr) * ldb + sc;
  const unsigned short* Bg1 = Bg0 + 64 * ldb;
  f32x4 acc[2][4];
#pragma unroll
  for (int i = 0; i < 2; i++)
#pragma unroll
    for (int j = 0; j < 4; j++) acc[i][j] = (f32x4){0.f, 0.f, 0.f, 0.f};

  auto compute = [&](int cur) {
    bf16x8 af[2], bfr[4];
#pragma unroll
    for (int mt = 0; mt < 2; mt++)
      af[mt] = *(const bf16x8*)&As[cur][(mw + mt * 16 + l15) * 40 + quad * 8];
#pragma unroll
    for (int nt = 0; nt < 4; nt++)
      bfr[nt] = *(const bf16x8*)&Bs[cur][(nw + nt * 16 + l15) * 40 + quad * 8];
#pragma unroll
    for (int mt = 0; mt < 2; mt++)
#pragma unroll
      for (int nt = 0; nt < 4; nt++)
        acc[mt][nt] = __builtin_amdgcn_mfma_f32_16x16x32_bf16(af[mt], bfr[nt], acc[mt][nt], 0, 0, 0);
  };

  // prologue: L0 -> buf0 directly; L1 -> set1; L2 -> set0
  int4 A0, G00, G10, A1, G01, G11;
  A0  = *(const int4*)(Ag0 + kb0);
  G00 = *(const int4*)(Bg0 + kb0);
  G10 = *(const int4*)(Bg1 + kb0);
  *(int4*)&As[0][sr * 40 + sc] = A0;
  *(int4*)&Bs[0][sr * 40 + sc] = G00;
  *(int4*)&Bs[0][(sr + 64) * 40 + sc] = G10;
  A1  = *(const int4*)(Ag0 + kb0 + 32);
  G01 = *(const int4*)(Bg0 + kb0 + 32);
  G11 = *(const int4*)(Bg1 + kb0 + 32);
  A0  = *(const int4*)(Ag0 + kb0 + 64);
  G00 = *(const int4*)(Bg0 + kb0 + 64);
  G10 = *(const int4*)(Bg1 + kb0 + 64);

  for (int ip = 0; ip < nIter; ip += 2) {
    __syncthreads();
    // store L(ip+1) -> buf1 (always valid: nIter even)
    *(int4*)&As[1][sr * 40 + sc] = A1;
    *(int4*)&Bs[1][sr * 40 + sc] = G01;
    *(int4*)&Bs[1][(sr + 64) * 40 + sc] = G11;
    if (ip + 3 < nIter) {
      int kb = kb0 + (ip + 3) * 32;
      A1  = *(const int4*)(Ag0 + kb);
      G01 = *(const int4*)(Bg0 + kb);
      G11 = *(const int4*)(Bg1 + kb);
    }
    compute(0);
    __syncthreads();
    if (ip + 2 < nIter) {
      *(int4*)&As[0][sr * 40 + sc] = A0;
      *(int4*)&Bs[0][sr * 40 + sc] = G00;
      *(int4*)&Bs[0][(sr + 64) * 40 + sc] = G10;
    }
    if (ip + 4 < nIter) {
      int kb = kb0 + (ip + 4) * 32;
      A0  = *(const int4*)(Ag0 + kb);
      G00 = *(const int4*)(Bg0 + kb);
      G10 = *(const int4*)(Bg1 + kb);
    }
    compute(1);
  }

  float* dfz = df + (size_t)zz * TP * ldc;
#pragma unroll
  for (int mt = 0; mt < 2; mt++) {
#pragma unroll
    for (int nt = 0; nt < 4; nt++) {
#pragma unroll
      for (int r = 0; r < 4; r++) {
        int row = rowBase + mw + mt * 16 + quad * 4 + r;
        int col = colBase + nw + nt * 16 + l15;
        float v = acc[mt][nt][r];
        if (mode == 0) {
          int seg = col >> 9, cc = col & 511;
          const float* bs = seg == 0 ? b0 : seg == 1 ? b1 : b2;
          unsigned short* dst = seg == 0 ? d0 : seg == 1 ? d1 : d2;
          int hd = cc >> 6, d = cc & 63;
          float t = v + bs[cc];
          if (seg == 0) t *= 0.180336880111f;  // 0.125 * log2(e) folded into Q
          dst[(hd * TP + row) * 64 + d] = f2bf(t);
        } else if (mode == 1) {
          dfz[row * ldc + col] = v;
        } else {
          float t = v + b0[col];
          t = t >= 0.f ? t : 0.01f * t;
          d0[row * ldc + col] = f2bf(t);
        }
      }
    }
  }
}

// ---------------- V transpose: vh [h][TP][64] -> vt [h][64][TK] ----------------

__global__ __launch_bounds__(256) void vt_trans(
    const unsigned short* __restrict__ vh, unsigned short* __restrict__ vt)
{
  __shared__ unsigned short t[64 * 72];
  int kt = blockIdx.x, h = blockIdx.y;
  int tid = threadIdx.x;
  int r0 = tid >> 3, cs = (tid & 7) * 8;
  const unsigned short* src = vh + (h * TP + kt * 64 + r0) * 64 + cs;
  *(int4*)&t[r0 * 72 + cs] = *(const int4*)src;
  *(int4*)&t[(r0 + 32) * 72 + cs] = *(const int4*)(src + 32 * 64);
  __syncthreads();
  int d = tid >> 2, c0 = (tid & 3) * 16;
  unsigned short vals[16];
#pragma unroll
  for (int j = 0; j < 16; j++) vals[j] = t[(c0 + j) * 72 + d];
  unsigned short* dst = vt + (h * 64 + d) * TK + kt * 64 + c0;
  *(int4*)dst = *(int4*)&vals[0];
  *(int4*)(dst + 8) = *(int4*)&vals[8];
}

// ---------------- split-KV flash attention: 128-row q-tiles, shift-free exp2 ---------
// grid (17 q-tiles, 8 heads, FSPLIT); split z handles tiles kt = z, z+FSPLIT, ...
// 4 waves; wave w owns q rows [w*32, w*32+32). Next tile's K/V/pos prefetched in regs.
// Ps write->read is wave-local (rows w*32..w*32+31): no barrier before PV.
// Row-sum l via ones-column 5th V n-tile (O[*][4]). Opart bf16; m == 0 implied.
// NOTE: Opart/lbuf row stride is TP (q rows are TP-padded with 128-tiles) — TK stride
// overflowed into the next (z,h) slice (round-6 bug).

__global__ __launch_bounds__(256) void flash_attn(
    const unsigned short* __restrict__ qh, const unsigned short* __restrict__ kh,
    const unsigned short* __restrict__ vt, const unsigned short* __restrict__ posb,
    unsigned short* __restrict__ Opart, float* __restrict__ lbuf)
{
  __shared__ unsigned short Ks[64 * 72];
  __shared__ unsigned short Vs[80 * 88];   // rows 0-63: V^T; rows 64-79: ones-col tile
  __shared__ unsigned short Ps[128 * 72];
  __shared__ float pt[40 * 24];
  const int tid = threadIdx.x;
  const int lane = tid & 63, wave = tid >> 6;
  const int l15 = lane & 15, quad = lane >> 4;
  const int qt = blockIdx.x, h = blockIdx.y, z = blockIdx.z;
  const int q0 = qt * 128;
  const int wbase = wave * 32;
  bf16x8 qf[2][2];
#pragma unroll
  for (int mt = 0; mt < 2; mt++) {
    const unsigned short* qbp = qh + (h * TP + q0 + wbase + mt * 16 + l15) * 64;
    qf[mt][0] = *(const bf16x8*)(qbp + quad * 8);
    qf[mt][1] = *(const bf16x8*)(qbp + 32 + quad * 8);
  }
  f32x4 O[2][5];
#pragma unroll
  for (int mt = 0; mt < 2; mt++)
#pragma unroll
    for (int nt = 0; nt < 5; nt++) O[mt][nt] = (f32x4){0.f, 0.f, 0.f, 0.f};
  for (int idx = tid; idx < 16 * 88; idx += 256) {
    int rr = idx / 88, cc = idx - rr * 88;
    Vs[(64 + rr) * 88 + cc] = (rr == 0) ? 0x3F80 : 0;
  }
  const int oq0 = q0 < 8 ? q0 : 8 + ((q0 - 8) >> 2);
  const int qe = min(q0 + 127, T_TOK - 1);
  const int nq = (qe < 8 ? qe : 8 + ((qe - 8) >> 2)) - oq0 + 1;   // <= 38
  int myq[2][4];
#pragma unroll
  for (int mt = 0; mt < 2; mt++)
#pragma unroll
    for (int r = 0; r < 4; r++) {
      int qr = q0 + wbase + mt * 16 + quad * 4 + r;
      myq[mt][r] = (qr < 8 ? qr : 8 + ((qr - 8) >> 2)) - oq0;
    }
  const int sr = tid >> 3, sc = (tid & 7) * 8;
  const unsigned short* kgb = kh + (h * TP + sr) * 64 + sc;
  const unsigned short* vgb = vt + (h * 64 + sr) * TK + sc;

  const int nT = (33 - z + FSPLIT - 1) / FSPLIT;
  int kb = z * 64;
  // prefetch tile 0
  int4 kv0 = *(const int4*)(kgb + kb * 64);
  int4 kv1 = *(const int4*)(kgb + (kb + 32) * 64);
  int4 vv0 = *(const int4*)(vgb + kb);
  int4 vv1 = *(const int4*)(vgb + 32 * TK + kb);
  float ppf[4];
  {
    int ok0n = kb < 8 ? kb : 8 + ((kb - 8) >> 2);
    int ken = min(kb + 63, T_TOK - 1);
    int nkn = (ken < 8 ? ken : 8 + ((ken - 8) >> 2)) - ok0n + 1;
#pragma unroll
    for (int u = 0; u < 4; u++) {
      int e = tid + 256 * u;
      int i = e / 24, j = e - i * 24;
      ppf[u] = (i < nq && j < nkn) ? bf2f(posb[(h * NORIG + oq0 + i) * NORIG + ok0n + j]) : 0.f;
    }
  }

  for (int it = 0; it < nT; ++it) {
    const int kbCur = kb;
    const int ok0c = kbCur < 8 ? kbCur : 8 + ((kbCur - 8) >> 2);
    __syncthreads();                       // prev tile's LDS reads complete
    *(int4*)&Ks[sr * 72 + sc] = kv0;
    *(int4*)&Ks[(sr + 32) * 72 + sc] = kv1;
    *(int4*)&Vs[sr * 88 + sc] = vv0;
    *(int4*)&Vs[(sr + 32) * 88 + sc] = vv1;
#pragma unroll
    for (int u = 0; u < 4; u++) {
      int e = tid + 256 * u;
      int i = e / 24, j = e - i * 24;
      if (i < 40) pt[i * 24 + j] = ppf[u];
    }
    __syncthreads();
    kb += FSPLIT * 64;
    if (it + 1 < nT) {                     // prefetch next tile during compute
      kv0 = *(const int4*)(kgb + kb * 64);
      kv1 = *(const int4*)(kgb + (kb + 32) * 64);
      vv0 = *(const int4*)(vgb + kb);
      vv1 = *(const int4*)(vgb + 32 * TK + kb);
      int ok0n = kb < 8 ? kb : 8 + ((kb - 8) >> 2);
      int ken = min(kb + 63, T_TOK - 1);
      int nkn = (ken < 8 ? ken : 8 + ((ken - 8) >> 2)) - ok0n + 1;
#pragma unroll
      for (int u = 0; u < 4; u++) {
        int e = tid + 256 * u;
        int i = e / 24, j = e - i * 24;
        ppf[u] = (i < nq && j < nkn) ? bf2f(posb[(h * NORIG + oq0 + i) * NORIG + ok0n + j]) : 0.f;
      }
    }
    // S = Q K^T  (2 m-frags x 4 n-frags)
    f32x4 S[2][4];
#pragma unroll
    for (int mt = 0; mt < 2; mt++)
#pragma unroll
      for (int nt = 0; nt < 4; nt++) S[mt][nt] = (f32x4){0.f, 0.f, 0.f, 0.f};
#pragma unroll
    for (int nt = 0; nt < 4; nt++) {
      bf16x8 kf0 = *(const bf16x8*)&Ks[(nt * 16 + l15) * 72 + quad * 8];
      bf16x8 kf1 = *(const bf16x8*)&Ks[(nt * 16 + l15) * 72 + 32 + quad * 8];
#pragma unroll
      for (int mt = 0; mt < 2; mt++) {
        S[mt][nt] = __builtin_amdgcn_mfma_f32_16x16x32_bf16(qf[mt][0], kf0, S[mt][nt], 0, 0, 0);
        S[mt][nt] = __builtin_amdgcn_mfma_f32_16x16x32_bf16(qf[mt][1], kf1, S[mt][nt], 0, 0, 0);
      }
    }
    int okp[4]; bool cval[4];
#pragma unroll
    for (int nt = 0; nt < 4; nt++) {
      int c = kbCur + nt * 16 + l15;
      cval[nt] = c < T_TOK;
      okp[nt] = (c < 8 ? c : 8 + ((c - 8) >> 2)) - ok0c;
    }
#pragma unroll
    for (int mt = 0; mt < 2; mt++) {
      const int prb = wbase + mt * 16 + quad * 4;
#pragma unroll
      for (int nt = 0; nt < 4; nt++) {
        const int cidx = nt * 16 + l15;
        float e0, e1, e2, e3;
        {
          float a0 = cval[nt] ? fminf(S[mt][nt][0] + pt[myq[mt][0] * 24 + okp[nt]], 86.f) : -1e30f;
          float a1 = cval[nt] ? fminf(S[mt][nt][1] + pt[myq[mt][1] * 24 + okp[nt]], 86.f) : -1e30f;
          float a2 = cval[nt] ? fminf(S[mt][nt][2] + pt[myq[mt][2] * 24 + okp[nt]], 86.f) : -1e30f;
          float a3 = cval[nt] ? fminf(S[mt][nt][3] + pt[myq[mt][3] * 24 + okp[nt]], 86.f) : -1e30f;
          e0 = EXP2(a0); e1 = EXP2(a1); e2 = EXP2(a2); e3 = EXP2(a3);
        }
        unsigned u01 = pk2bf(e0, e1), u23 = pk2bf(e2, e3);
        Ps[(prb + 0) * 72 + cidx] = (unsigned short)u01;
        Ps[(prb + 1) * 72 + cidx] = (unsigned short)(u01 >> 16);
        Ps[(prb + 2) * 72 + cidx] = (unsigned short)u23;
        Ps[(prb + 3) * 72 + cidx] = (unsigned short)(u23 >> 16);
      }
    }
    // O += P V  — Ps rows are wave-local: no barrier
    bf16x8 pa[2][2];
#pragma unroll
    for (int mt = 0; mt < 2; mt++) {
      pa[mt][0] = *(const bf16x8*)&Ps[(wbase + mt * 16 + l15) * 72 + quad * 8];
      pa[mt][1] = *(const bf16x8*)&Ps[(wbase + mt * 16 + l15) * 72 + 32 + quad * 8];
    }
#pragma unroll
    for (int nt = 0; nt < 5; nt++) {
      bf16x8 vb0 = *(const bf16x8*)&Vs[(nt * 16 + l15) * 88 + quad * 8];
      bf16x8 vb1 = *(const bf16x8*)&Vs[(nt * 16 + l15) * 88 + 32 + quad * 8];
#pragma unroll
      for (int mt = 0; mt < 2; mt++) {
        O[mt][nt] = __builtin_amdgcn_mfma_f32_16x16x32_bf16(pa[mt][0], vb0, O[mt][nt], 0, 0, 0);
        O[mt][nt] = __builtin_amdgcn_mfma_f32_16x16x32_bf16(pa[mt][1], vb1, O[mt][nt], 0, 0, 0);
      }
    }
  }
#pragma unroll
  for (int mt = 0; mt < 2; mt++) {
#pragma unroll
    for (int r = 0; r < 4; r++) {
      int orow = q0 + wbase + mt * 16 + quad * 4 + r;
      size_t base = ((size_t)(z * NHEAD + h) * TP + orow);   // TP stride (bug fix)
      if (l15 == 0) lbuf[base] = O[mt][4][r];
#pragma unroll
      for (int nt = 0; nt < 4; nt++)
        Opart[base * 64 + nt * 16 + l15] = f2bf(O[mt][nt][r]);
    }
  }
}

// ---------------- merge flash splits (pure sum; m==0) -> ob (bf16 [T][512]) ---------

__global__ __launch_bounds__(256) void flash_merge(
    const unsigned short* __restrict__ Opart, const float* __restrict__ lbuf,
    unsigned short* __restrict__ ob)
{
  int idx = blockIdx.x * 256 + threadIdx.x;
  if (idx >= T_TOK * HIDDEN) return;
  int row = idx >> 9, c = idx & 511;
  int h = c >> 6, d = c & 63;
  float num = 0.f, den = 0.f;
#pragma unroll
  for (int s = 0; s < FSPLIT; s++) {
    size_t base = ((size_t)(s * NHEAD + h) * TP + row);     // TP stride (bug fix)
    den += lbuf[base];
    num += bf2f(Opart[base * 64 + d]);
  }
  ob[idx] = f2bf(num / den);
}

// ---------------- residual + bias + 4-way split-K sum + LN, fp32 + bf16 mirror -------

__global__ __launch_bounds__(256) void ln_residual4(
    float* __restrict__ x, const float* __restrict__ parts,
    const float* __restrict__ bias,
    const float* __restrict__ g, const float* __restrict__ b,
    unsigned short* __restrict__ xb)
{
  __shared__ float sb[4];
  int row = blockIdx.x;
  int j0 = threadIdx.x, j1 = threadIdx.x + 256;
  int base = row * HIDDEN;
  const size_t ss = (size_t)TP * HIDDEN;
  float v0 = x[base + j0] + bias[j0] + parts[base + j0] + parts[ss + base + j0]
           + parts[2 * ss + base + j0] + parts[3 * ss + base + j0];
  float v1 = x[base + j1] + bias[j1] + parts[base + j1] + parts[ss + base + j1]
           + parts[2 * ss + base + j1] + parts[3 * ss + base + j1];
  float s1 = blockReduceSum(v0 + v1, sb);
  float s2 = blockReduceSum(v0 * v0 + v1 * v1, sb);
  float m = s1 * (1.0f / HIDDEN);
  float var = s2 * (1.0f / HIDDEN) - m * m;
  float inv = rsqrtf(var + 1e-5f);
  float y0 = (v0 - m) * inv * g[j0] + b[j0];
  float y1 = (v1 - m) * inv * g[j1] + b[j1];
  x[base + j0] = y0;
  x[base + j1] = y1;
  xb[base + j0] = f2bf(y0);
  xb[base + j1] = f2bf(y1);
}

__global__ __launch_bounds__(256) void copy_out(
    const float4* __restrict__ src, float4* __restrict__ dst, int n4)
{
  int i = blockIdx.x * 256 + threadIdx.x;
  if (i < n4) dst[i] = src[i];
}

// ---------------- driver ----------------

extern "C" void kernel_launch(void* const* d_in, const int* in_sizes, int n_in,
                              void* d_out, int out_size, void* d_ws, size_t ws_size,
                              hipStream_t stream) {
  const float* obj   = (const float*)d_in[0];
  const float* st0   = (const float*)d_in[2];
  const int*   rpe_a = (const int*)d_in[3];
  const int*   rpe_d = (const int*)d_in[4];
  const float* mask  = (const float*)d_in[5];
  const float* Wpg = (const float*)d_in[6];  const float* bpg = (const float*)d_in[7];
  const float* pg_g = (const float*)d_in[8]; const float* pg_b = (const float*)d_in[9];
  const float* Wps = (const float*)d_in[10]; const float* bps = (const float*)d_in[11];
  const float* ps_g = (const float*)d_in[12];const float* ps_b = (const float*)d_in[13];
  const float* emb_a = (const float*)d_in[14];
  const float* emb_d = (const float*)d_in[15];
  const float* Wq = (const float*)d_in[16]; const float* bq = (const float*)d_in[17];
  const float* Wk = (const float*)d_in[18]; const float* bk = (const float*)d_in[19];
  const float* Wv = (const float*)d_in[20]; const float* bv = (const float*)d_in[21];
  const float* Wo = (const float*)d_in[22]; const float* bo = (const float*)d_in[23];
  const float* W1 = (const float*)d_in[24]; const float* b1 = (const float*)d_in[25];
  const float* W2 = (const float*)d_in[26]; const float* b2 = (const float*)d_in[27];
  const float* ln1_g = (const float*)d_in[28]; const float* ln1_b = (const float*)d_in[29];
  const float* ln2_g = (const float*)d_in[30]; const float* ln2_b = (const float*)d_in[31];

  // ---- workspace layout ----
  char* p = (char*)d_ws;
  auto alloc = [&](size_t bytes) { char* q = p; p += (bytes + 255) & ~(size_t)255; return q; };
  float*          x      = (float*)alloc((size_t)T_TOK * HIDDEN * 4);
  unsigned short* xb     = (unsigned short*)alloc((size_t)TP * HIDDEN * 2);
  // union1: {qhb,khb,vhb,vtb} (attention phase) | hb (FFN phase)
  char*           u1     = (char*)alloc((size_t)TP * FFDIM * 2);
  unsigned short* qhb    = (unsigned short*)u1;
  unsigned short* khb    = qhb + (size_t)NHEAD * TP * ADIM;
  unsigned short* vhb    = khb + (size_t)NHEAD * TP * ADIM;
  unsigned short* vtb    = vhb + (size_t)NHEAD * TP * ADIM;
  unsigned short* hb     = (unsigned short*)u1;
  unsigned short* ob     = (unsigned short*)alloc((size_t)TP * HIDDEN * 2);
  // union2: {Opart(bf16, TP-strided)+lbuf} (flash) | parts (split-K GEMM fp32)
  size_t opartB = (size_t)FSPLIT * NHEAD * TP * ADIM * 2;
  size_t partsB = (size_t)NSPLIT * TP * HIDDEN * 4;
  size_t u2B = opartB + (size_t)FSPLIT * NHEAD * TP * 4;
  if (partsB > u2B) u2B = partsB;
  char*           u2     = (char*)alloc(u2B);
  unsigned short* Opart  = (unsigned short*)u2;
  float*          lbb    = (float*)(u2 + opartB);
  float*          parts  = (float*)u2;
  unsigned short* posb   = (unsigned short*)alloc((size_t)NHEAD * NORIG * NORIG * 2);
  size_t perLayerW = ((size_t)1536 * 512 + 512 * 512 + 2048 * 512 + 512 * 2048) * 2;
  size_t baseUsed = (size_t)(p - (char*)d_ws);
  bool hoist = (baseUsed + 6 * perLayerW + 2048) <= ws_size;
  int nWsets = hoist ? 6 : 1;
  unsigned short* Wsets = (unsigned short*)alloc(perLayerW * nWsets);
  if ((size_t)(p - (char*)d_ws) > ws_size) return;

  auto wq_t = [&](int l) { return Wsets + (hoist ? l : 0) * (perLayerW / 2); };
  auto wo_t = [&](int l) { return wq_t(l) + (size_t)1536 * 512; };
  auto w1_t = [&](int l) { return wo_t(l) + (size_t)512 * 512; };
  auto w2_t = [&](int l) { return w1_t(l) + (size_t)2048 * 512; };

  float* out = (float*)d_out;

  embed_kernel<<<T_TOK, 256, 0, stream>>>(obj, st0, Wpg, bpg, pg_g, pg_b,
                                          Wps, bps, ps_g, ps_b, x, xb);
  padzero<<<((TP - T_TOK) * HIDDEN + 255) / 256, 256, 0, stream>>>(xb);
  posbuild<<<NORIG, 256, 0, stream>>>(rpe_a, rpe_d, emb_a, emb_d, mask, posb);
  if (hoist) {
    for (int l = 0; l < NLAYER; l++)
      wtrans<<<768, 256, 0, stream>>>(
          Wq + l * 512 * 512, Wk + l * 512 * 512, Wv + l * 512 * 512,
          Wo + l * 512 * 512, W1 + l * 512 * 2048, W2 + l * 2048 * 512,
          wq_t(l), wo_t(l), w1_t(l), w2_t(l));
  }

  for (int l = 0; l < NLAYER; l++) {
    if (!hoist) {
      wtrans<<<768, 256, 0, stream>>>(
          Wq + l * 512 * 512, Wk + l * 512 * 512, Wv + l * 512 * 512,
          Wo + l * 512 * 512, W1 + l * 512 * 2048, W2 + l * 2048 * 512,
          wq_t(l), wo_t(l), w1_t(l), w2_t(l));
    }
    // QKV (N=1536 packed)
    gemm_bt<<<dim3(12, 34, 1), 256, 0, stream>>>(
        xb, HIDDEN, wq_t(l), HIDDEN, HIDDEN, 0,
        bq + l * 512, bk + l * 512, bv + l * 512, qhb, khb, vhb, nullptr, 0);
    vt_trans<<<dim3(33, 8), 256, 0, stream>>>(vhb, vtb);
    flash_attn<<<dim3(17, 8, FSPLIT), 256, 0, stream>>>(
        qhb, khb, vtb, posb, Opart, lbb);
    flash_merge<<<(T_TOK * HIDDEN + 255) / 256, 256, 0, stream>>>(Opart, lbb, ob);
    // O projection: split-K(4) -> parts, reduce fused into LN
    gemm_bt<<<dim3(4, 34, NSPLIT), 256, 0, stream>>>(
        ob, HIDDEN, wo_t(l), HIDDEN, HIDDEN, 1,
        nullptr, nullptr, nullptr, nullptr, nullptr, nullptr, parts, HIDDEN);
    ln_residual4<<<T_TOK, 256, 0, stream>>>(x, parts, bo + l * 512,
                                            ln1_g + l * 512, ln1_b + l * 512, xb);
    // FFN1 -> hb (bf16, leaky)
    gemm_bt<<<dim3(16, 34, 1), 256, 0, stream>>>(
        xb, HIDDEN, w1_t(l), HIDDEN, HIDDEN, 2,
        b1 + l * 2048, nullptr, nullptr, hb, nullptr, nullptr, nullptr, FFDIM);
    // FFN2: split-K(4) -> parts
    gemm_bt<<<dim3(4, 34, NSPLIT), 256, 0, stream>>>(
        hb, FFDIM, w2_t(l), FFDIM, FFDIM, 1,
        nullptr, nullptr, nullptr, nullptr, nullptr, nullptr, parts, HIDDEN);
    ln_residual4<<<T_TOK, 256, 0, stream>>>(x, parts, b2 + l * 512,
                                            ln2_g + l * 512, ln2_b + l * 512, xb);
  }

  int n4 = T_TOK * HIDDEN / 4;
  copy_out<<<(n4 + 255) / 256, 256, 0, stream>>>((const float4*)x, (float4*)out, n4);
}

// Round 8
// 957.835 us; speedup vs baseline: 1.1314x; 1.1314x over previous
//
#include <hip/hip_runtime.h>
#include <math.h>

#define T_TOK 2056
#define TP 2176      // 17*128  M-padded rows
#define TK 2112      // 33*64   KV-padded rows
#define HIDDEN 512
#define NHEAD 8
#define ADIM 64
#define FFDIM 2048
#define NLAYER 6
#define NORIG 520
#define NOBJ 8
#define NSPLIT 4     // GEMM K-splits
#define FSPLIT 8     // flash KV splits

typedef float f32x4 __attribute__((ext_vector_type(4)));
typedef __attribute__((__ext_vector_type__(8))) __bf16 bf16x8;

#if __has_builtin(__builtin_amdgcn_exp2f)
#define EXP2(x) __builtin_amdgcn_exp2f(x)
#else
#define EXP2(x) exp2f(x)
#endif

__device__ __forceinline__ unsigned short f2bf(float f) {
  unsigned int u = __float_as_uint(f);
  u += 0x7FFFu + ((u >> 16) & 1u);
  return (unsigned short)(u >> 16);
}
__device__ __forceinline__ float bf2f(unsigned short u) {
  return __uint_as_float(((unsigned int)u) << 16);
}
// packed f32x2 -> bf16x2 (lo = a, hi = b); HW single-op on gfx950
__device__ __forceinline__ unsigned pk2bf(float a, float b) {
#if __has_builtin(__builtin_amdgcn_cvt_pk_bf16_f32)
  auto v = __builtin_amdgcn_cvt_pk_bf16_f32(a, b);
  unsigned u;
  __builtin_memcpy(&u, &v, 4);
  return u;
#else
  return (unsigned)f2bf(a) | ((unsigned)f2bf(b) << 16);
#endif
}

// async global -> LDS, 16 B per lane (global_load_lds_dwordx4); lane i of the wave
// lands at firstlane(lptr) + i*16, so lptr must equal base + lane*16 in lane order.
__device__ __forceinline__ void gl_lds16(const void* g, void* l) {
  __builtin_amdgcn_global_load_lds(
      (const __attribute__((address_space(1))) void*)g,
      (__attribute__((address_space(3))) void*)l, 16, 0, 0);
}

// ---------------- block reduction helpers (256 threads = 4 waves) ----------------

__device__ inline float blockReduceSum(float v, float* sb) {
#pragma unroll
  for (int off = 32; off > 0; off >>= 1) v += __shfl_down(v, off, 64);
  int wid = threadIdx.x >> 6;
  __syncthreads();
  if ((threadIdx.x & 63) == 0) sb[wid] = v;
  __syncthreads();
  return sb[0] + sb[1] + sb[2] + sb[3];
}

// ---------------- token embedding: project + LN + leaky_relu (fp32 + bf16 mirror) ----

__global__ __launch_bounds__(256) void embed_kernel(
    const float* __restrict__ obj, const float* __restrict__ st0,
    const float* __restrict__ Wpg, const float* __restrict__ bpg,
    const float* __restrict__ pg_g, const float* __restrict__ pg_b,
    const float* __restrict__ Wps, const float* __restrict__ bps,
    const float* __restrict__ ps_g, const float* __restrict__ ps_b,
    float* __restrict__ x, unsigned short* __restrict__ xb)
{
  __shared__ float sb[4];
  int t = blockIdx.x;
  int j0 = threadIdx.x, j1 = threadIdx.x + 256;
  float a0, a1;
  const float *g, *b;
  if (t < NOBJ) {
    a0 = bpg[j0]; a1 = bpg[j1];
    const float* in = obj + t * 100;
    for (int i = 0; i < 100; i++) {
      float w = in[i];
      a0 += w * Wpg[i * HIDDEN + j0];
      a1 += w * Wpg[i * HIDDEN + j1];
    }
    g = pg_g; b = pg_b;
  } else {
    int tt = t - NOBJ, s = tt >> 2, p = tt & 3;
    float c0 = st0[s * 10 + p * 2], c1 = st0[s * 10 + p * 2 + 1];
    a0 = bps[j0] + c0 * Wps[j0] + c1 * Wps[HIDDEN + j0];
    a1 = bps[j1] + c0 * Wps[j1] + c1 * Wps[HIDDEN + j1];
    g = ps_g; b = ps_b;
  }
  float s1 = blockReduceSum(a0 + a1, sb);
  float s2 = blockReduceSum(a0 * a0 + a1 * a1, sb);
  float m = s1 * (1.0f / HIDDEN);
  float var = s2 * (1.0f / HIDDEN) - m * m;
  float inv = rsqrtf(var + 1e-5f);
  float y0 = (a0 - m) * inv * g[j0] + b[j0];
  float y1 = (a1 - m) * inv * g[j1] + b[j1];
  y0 = y0 >= 0.f ? y0 : 0.01f * y0;
  y1 = y1 >= 0.f ? y1 : 0.01f * y1;
  x[t * HIDDEN + j0] = y0;
  x[t * HIDDEN + j1] = y1;
  xb[t * HIDDEN + j0] = f2bf(y0);
  xb[t * HIDDEN + j1] = f2bf(y1);
}

// zero xb pad rows (re-run every launch; ws is re-poisoned)
__global__ __launch_bounds__(256) void padzero(unsigned short* __restrict__ xb) {
  int i = blockIdx.x * 256 + threadIdx.x;
  if (i < (TP - T_TOK) * HIDDEN) xb[T_TOK * HIDDEN + i] = 0;
}

// ---------------- precompute rel-pos bias table: posb[h][520][520] (bf16) ----------
// posb = ((emb_a[rpe_a]+emb_d[rpe_d]) * 0.125 + mask) * log2(e)   (layer-invariant)

__global__ __launch_bounds__(256) void posbuild(
    const int* __restrict__ rpe_a, const int* __restrict__ rpe_d,
    const float* __restrict__ emb_a, const float* __restrict__ emb_d,
    const float* __restrict__ mask, unsigned short* __restrict__ posb)
{
  int i = blockIdx.x;
  for (int j = threadIdx.x; j < NORIG; j += 256) {
    int a = rpe_a[i * NORIG + j];
    int d = rpe_d[i * NORIG + j];
    float mk = mask[i * NORIG + j];
#pragma unroll
    for (int h = 0; h < NHEAD; h++) {
      float v = ((emb_a[a * NHEAD + h] + emb_d[d * NHEAD + h]) * 0.125f + mk) * 1.44269504f;
      posb[(h * NORIG + i) * NORIG + j] = f2bf(v);
    }
  }
}

// ---------------- weight transpose+convert: fp32 [K][N] -> bf16 [N][K] ----------------

__global__ __launch_bounds__(256) void wtrans(
    const float* __restrict__ Wq, const float* __restrict__ Wk, const float* __restrict__ Wv,
    const float* __restrict__ Wo, const float* __restrict__ W1, const float* __restrict__ W2,
    unsigned short* __restrict__ Wqkvt, unsigned short* __restrict__ Wot,
    unsigned short* __restrict__ W1t, unsigned short* __restrict__ W2t)
{
  __shared__ float t[64 * 65];
  int b = blockIdx.x;
  const float* src; unsigned short* dst; int N, K, tk, tn;
  if (b < 192) {
    int m = b >> 6, bb = b & 63;
    src = m == 0 ? Wq : m == 1 ? Wk : Wv;
    dst = Wqkvt + m * 512 * 512;
    K = 512; N = 512; tk = bb & 7; tn = bb >> 3;
  } else if (b < 256) {
    int bb = b - 192; src = Wo; dst = Wot; K = 512; N = 512; tk = bb & 7; tn = bb >> 3;
  } else if (b < 512) {
    int bb = b - 256; src = W1; dst = W1t; K = 512; N = 2048; tk = bb & 7; tn = bb >> 3;
  } else {
    int bb = b - 512; src = W2; dst = W2t; K = 2048; N = 512; tk = bb & 31; tn = bb >> 5;
  }
  int k0 = tk * 64, n0 = tn * 64;
  int tid = threadIdx.x;
  int r = tid >> 2, c0 = (tid & 3) * 16;
  const float* sp = src + (k0 + r) * N + n0 + c0;
#pragma unroll
  for (int q = 0; q < 4; q++) {
    float4 f = *(const float4*)(sp + q * 4);
    t[r * 65 + c0 + q * 4 + 0] = f.x;
    t[r * 65 + c0 + q * 4 + 1] = f.y;
    t[r * 65 + c0 + q * 4 + 2] = f.z;
    t[r * 65 + c0 + q * 4 + 3] = f.w;
  }
  __syncthreads();
  unsigned short vals[16];
#pragma unroll
  for (int j = 0; j < 16; j++) vals[j] = f2bf(t[(c0 + j) * 65 + r]);
  unsigned short* dp = dst + (n0 + r) * K + k0 + c0;
  *(int4*)dp = *(int4*)&vals[0];
  *(int4*)(dp + 8) = *(int4*)&vals[8];
}

// ---------------- MFMA GEMM: C[M=2176][N] = A[.][K] * Bt[N][K]^T, bf16 in / fp32 acc ----
// BM=64, BN=128, BK=32; 4 waves each 32x64. Staging via async global_load_lds (16B/lane,
// m97 pattern): LDS rows unpadded (32 elems = 64 B), XOR swizzle kchunk^( (row>>1)&3 )
// on store mapping + mirrored ds_read offsets => fragment reads are 2-way aliased (free).
// Double-buffered, ONE __syncthreads per k-iter (drains vmcnt + barrier).
// mode 0: +bias(seg) -> scatter bf16 to qh/kh/vh [head][TP][64]; Q scaled 0.125*log2e
// mode 1: split-K partial -> fp32 df[z][TP][ldc] (NO bias)
// mode 2: +bias, leaky -> bf16 d0

__global__ __launch_bounds__(256) void gemm_bt(
    const unsigned short* __restrict__ A, int lda,
    const unsigned short* __restrict__ Bt, int ldb, int K, int mode,
    const float* __restrict__ b0, const float* __restrict__ b1, const float* __restrict__ b2,
    unsigned short* __restrict__ d0, unsigned short* __restrict__ d1, unsigned short* __restrict__ d2,
    float* __restrict__ df, int ldc)
{
  __shared__ unsigned short As[2][64 * 32];
  __shared__ unsigned short Bs[2][128 * 32];
  const int tid = threadIdx.x;
  const int lane = tid & 63, wave = tid >> 6;
  const int l15 = lane & 15, quad = lane >> 4;
  const int rowBase = blockIdx.y * 64, colBase = blockIdx.x * 128;
  const int mw = (wave & 1) * 32, nw = (wave >> 1) * 64;
  const int zz = blockIdx.z;
  const int kLen = K / gridDim.z;
  const int kb0 = zz * kLen;
  const int nIter = kLen >> 5;
  // staging: thread tid -> LDS 16B slot tid (row = tid>>2, slot tid&3); global k-chunk
  // is XOR-swizzled so the read side is conflict-free.
  const int srow = tid >> 2;
  const int kchunk = (tid & 3) ^ ((srow >> 1) & 3);
  const unsigned short* Ag  = A  + (size_t)(rowBase + srow) * lda + kb0 + kchunk * 8;
  const unsigned short* Bg0 = Bt + (size_t)(colBase + srow) * ldb + kb0 + kchunk * 8;
  const unsigned short* Bg1 = Bg0 + (size_t)64 * ldb;
  // read-side swizzled offsets (elements), lane-constant across iters
  int aoff[2], boff[4];
#pragma unroll
  for (int mt = 0; mt < 2; mt++) {
    int row = mw + mt * 16 + l15;
    aoff[mt] = row * 32 + ((quad ^ ((row >> 1) & 3)) * 8);
  }
#pragma unroll
  for (int nt = 0; nt < 4; nt++) {
    int row = nw + nt * 16 + l15;
    boff[nt] = row * 32 + ((quad ^ ((row >> 1) & 3)) * 8);
  }
  f32x4 acc[2][4];
#pragma unroll
  for (int i = 0; i < 2; i++)
#pragma unroll
    for (int j = 0; j < 4; j++) acc[i][j] = (f32x4){0.f, 0.f, 0.f, 0.f};

  // issue iter-0 loads into buf0 (async)
  gl_lds16(Ag,  (unsigned short*)As[0] + tid * 8);
  gl_lds16(Bg0, (unsigned short*)Bs[0] + tid * 8);
  gl_lds16(Bg1, (unsigned short*)Bs[0] + 2048 + tid * 8);

  for (int it = 0; it < nIter; ++it) {
    const int cur = it & 1, nxt = cur ^ 1;
    __syncthreads();   // drains outstanding global_load_lds (vmcnt0) + barrier
    if (it + 1 < nIter) {
      int koff = (it + 1) * 32;
      gl_lds16(Ag + koff,  (unsigned short*)As[nxt] + tid * 8);
      gl_lds16(Bg0 + koff, (unsigned short*)Bs[nxt] + tid * 8);
      gl_lds16(Bg1 + koff, (unsigned short*)Bs[nxt] + 2048 + tid * 8);
    }
    bf16x8 af[2], bfr[4];
#pragma unroll
    for (int mt = 0; mt < 2; mt++)
      af[mt] = *(const bf16x8*)&As[cur][aoff[mt]];
#pragma unroll
    for (int nt = 0; nt < 4; nt++)
      bfr[nt] = *(const bf16x8*)&Bs[cur][boff[nt]];
#pragma unroll
    for (int mt = 0; mt < 2; mt++)
#pragma unroll
      for (int nt = 0; nt < 4; nt++)
        acc[mt][nt] = __builtin_amdgcn_mfma_f32_16x16x32_bf16(af[mt], bfr[nt], acc[mt][nt], 0, 0, 0);
  }

  float* dfz = df + (size_t)zz * TP * ldc;
#pragma unroll
  for (int mt = 0; mt < 2; mt++) {
#pragma unroll
    for (int nt = 0; nt < 4; nt++) {
#pragma unroll
      for (int r = 0; r < 4; r++) {
        int row = rowBase + mw + mt * 16 + quad * 4 + r;
        int col = colBase + nw + nt * 16 + l15;
        float v = acc[mt][nt][r];
        if (mode == 0) {
          int seg = col >> 9, cc = col & 511;
          const float* bs = seg == 0 ? b0 : seg == 1 ? b1 : b2;
          unsigned short* dst = seg == 0 ? d0 : seg == 1 ? d1 : d2;
          int hd = cc >> 6, d = cc & 63;
          float t = v + bs[cc];
          if (seg == 0) t *= 0.180336880111f;  // 0.125 * log2(e) folded into Q
          dst[(hd * TP + row) * 64 + d] = f2bf(t);
        } else if (mode == 1) {
          dfz[row * ldc + col] = v;
        } else {
          float t = v + b0[col];
          t = t >= 0.f ? t : 0.01f * t;
          d0[row * ldc + col] = f2bf(t);
        }
      }
    }
  }
}

// ---------------- V transpose: vh [h][TP][64] -> vt [h][64][TK] ----------------

__global__ __launch_bounds__(256) void vt_trans(
    const unsigned short* __restrict__ vh, unsigned short* __restrict__ vt)
{
  __shared__ unsigned short t[64 * 72];
  int kt = blockIdx.x, h = blockIdx.y;
  int tid = threadIdx.x;
  int r0 = tid >> 3, cs = (tid & 7) * 8;
  const unsigned short* src = vh + (h * TP + kt * 64 + r0) * 64 + cs;
  *(int4*)&t[r0 * 72 + cs] = *(const int4*)src;
  *(int4*)&t[(r0 + 32) * 72 + cs] = *(const int4*)(src + 32 * 64);
  __syncthreads();
  int d = tid >> 2, c0 = (tid & 3) * 16;
  unsigned short vals[16];
#pragma unroll
  for (int j = 0; j < 16; j++) vals[j] = t[(c0 + j) * 72 + d];
  unsigned short* dst = vt + (h * 64 + d) * TK + kt * 64 + c0;
  *(int4*)dst = *(int4*)&vals[0];
  *(int4*)(dst + 8) = *(int4*)&vals[8];
}

// ---------------- split-KV flash attention, shift-free exp2 softmax, pipelined -------
// (round-5 configuration: 64-row q-tiles, FSPLIT=8 — highest measured occupancy)
// grid (33 q-tiles, 8 heads, FSPLIT); split z handles tiles kt = z, z+FSPLIT, ...
// Next tile's K/V/pos prefetched into regs during current tile's compute.
// Ps write->read is wave-local: no barrier between epilogue and PV.
// Row-sum l via ones-column 5th V n-tile (O[4]). Opart bf16; m == 0 implied.

__global__ __launch_bounds__(256) void flash_attn(
    const unsigned short* __restrict__ qh, const unsigned short* __restrict__ kh,
    const unsigned short* __restrict__ vt, const unsigned short* __restrict__ posb,
    unsigned short* __restrict__ Opart, float* __restrict__ lbuf)
{
  __shared__ unsigned short Ks[64 * 72];
  __shared__ unsigned short Vs[80 * 88];   // rows 0-63: V^T; rows 64-79: ones-col tile
  __shared__ unsigned short Ps[64 * 72];
  __shared__ float pt[24 * 24];
  const int tid = threadIdx.x;
  const int lane = tid & 63, wave = tid >> 6;
  const int l15 = lane & 15, quad = lane >> 4;
  const int qt = blockIdx.x, h = blockIdx.y, z = blockIdx.z;
  const int q0 = qt * 64;
  const int qrow = q0 + wave * 16 + l15;
  const unsigned short* qbp = qh + (h * TP + qrow) * 64;
  bf16x8 qf0 = *(const bf16x8*)(qbp + quad * 8);
  bf16x8 qf1 = *(const bf16x8*)(qbp + 32 + quad * 8);
  f32x4 O[5];
#pragma unroll
  for (int nt = 0; nt < 5; nt++) O[nt] = (f32x4){0.f, 0.f, 0.f, 0.f};
  for (int idx = tid; idx < 16 * 88; idx += 256) {
    int rr = idx / 88, cc = idx - rr * 88;
    Vs[(64 + rr) * 88 + cc] = (rr == 0) ? 0x3F80 : 0;
  }
  const int oq0 = q0 < 8 ? q0 : 8 + ((q0 - 8) >> 2);
  const int qe = min(q0 + 63, T_TOK - 1);
  const int nq = (qe < 8 ? qe : 8 + ((qe - 8) >> 2)) - oq0 + 1;
  int myq[4];
#pragma unroll
  for (int r = 0; r < 4; r++) {
    int qr = q0 + wave * 16 + quad * 4 + r;
    myq[r] = (qr < 8 ? qr : 8 + ((qr - 8) >> 2)) - oq0;
  }
  const int sr = tid >> 3, sc = (tid & 7) * 8;
  const unsigned short* kgb = kh + (h * TP + sr) * 64 + sc;
  const unsigned short* vgb = vt + (h * 64 + sr) * TK + sc;
  const int ptrow = tid >> 3, ptc0 = (tid & 7) * 3;
  const bool prok = (ptrow < 24) && (ptrow < nq);

  const int nT = (33 - z + FSPLIT - 1) / FSPLIT;
  int kb = z * 64;
  // prefetch tile 0
  int4 kv0 = *(const int4*)(kgb + kb * 64);
  int4 kv1 = *(const int4*)(kgb + (kb + 32) * 64);
  int4 vv0 = *(const int4*)(vgb + kb);
  int4 vv1 = *(const int4*)(vgb + 32 * TK + kb);
  float ppf0, ppf1, ppf2;
  {
    int ok0n = kb < 8 ? kb : 8 + ((kb - 8) >> 2);
    int ken = min(kb + 63, T_TOK - 1);
    int nkn = (ken < 8 ? ken : 8 + ((ken - 8) >> 2)) - ok0n + 1;
    const unsigned short* prow = posb + (h * NORIG + oq0 + ptrow) * NORIG + ok0n;
    ppf0 = (prok && ptc0 + 0 < nkn) ? bf2f(prow[ptc0 + 0]) : 0.f;
    ppf1 = (prok && ptc0 + 1 < nkn) ? bf2f(prow[ptc0 + 1]) : 0.f;
    ppf2 = (prok && ptc0 + 2 < nkn) ? bf2f(prow[ptc0 + 2]) : 0.f;
  }

  for (int it = 0; it < nT; ++it) {
    const int kbCur = kb;
    const int ok0c = kbCur < 8 ? kbCur : 8 + ((kbCur - 8) >> 2);
    __syncthreads();                       // prev tile's LDS reads complete
    *(int4*)&Ks[sr * 72 + sc] = kv0;
    *(int4*)&Ks[(sr + 32) * 72 + sc] = kv1;
    *(int4*)&Vs[sr * 88 + sc] = vv0;
    *(int4*)&Vs[(sr + 32) * 88 + sc] = vv1;
    if (ptrow < 24) {
      pt[ptrow * 24 + ptc0 + 0] = ppf0;
      pt[ptrow * 24 + ptc0 + 1] = ppf1;
      pt[ptrow * 24 + ptc0 + 2] = ppf2;
    }
    __syncthreads();
    kb += FSPLIT * 64;
    if (it + 1 < nT) {                     // prefetch next tile during compute
      kv0 = *(const int4*)(kgb + kb * 64);
      kv1 = *(const int4*)(kgb + (kb + 32) * 64);
      vv0 = *(const int4*)(vgb + kb);
      vv1 = *(const int4*)(vgb + 32 * TK + kb);
      int ok0n = kb < 8 ? kb : 8 + ((kb - 8) >> 2);
      int ken = min(kb + 63, T_TOK - 1);
      int nkn = (ken < 8 ? ken : 8 + ((ken - 8) >> 2)) - ok0n + 1;
      const unsigned short* prow = posb + (h * NORIG + oq0 + ptrow) * NORIG + ok0n;
      ppf0 = (prok && ptc0 + 0 < nkn) ? bf2f(prow[ptc0 + 0]) : 0.f;
      ppf1 = (prok && ptc0 + 1 < nkn) ? bf2f(prow[ptc0 + 1]) : 0.f;
      ppf2 = (prok && ptc0 + 2 < nkn) ? bf2f(prow[ptc0 + 2]) : 0.f;
    }
    // S = Q K^T
    f32x4 S[4];
#pragma unroll
    for (int nt = 0; nt < 4; nt++) S[nt] = (f32x4){0.f, 0.f, 0.f, 0.f};
#pragma unroll
    for (int nt = 0; nt < 4; nt++) {
      bf16x8 kf0 = *(const bf16x8*)&Ks[(nt * 16 + l15) * 72 + quad * 8];
      bf16x8 kf1 = *(const bf16x8*)&Ks[(nt * 16 + l15) * 72 + 32 + quad * 8];
      S[nt] = __builtin_amdgcn_mfma_f32_16x16x32_bf16(qf0, kf0, S[nt], 0, 0, 0);
      S[nt] = __builtin_amdgcn_mfma_f32_16x16x32_bf16(qf1, kf1, S[nt], 0, 0, 0);
    }
    int okp[4]; bool cval[4];
#pragma unroll
    for (int nt = 0; nt < 4; nt++) {
      int c = kbCur + nt * 16 + l15;
      cval[nt] = c < T_TOK;
      okp[nt] = (c < 8 ? c : 8 + ((c - 8) >> 2)) - ok0c;
    }
    const int prb = wave * 16 + quad * 4;
#pragma unroll
    for (int nt = 0; nt < 4; nt++) {
      const int cidx = nt * 16 + l15;
      float a0 = cval[nt] ? fminf(S[nt][0] + pt[myq[0] * 24 + okp[nt]], 86.f) : -1e30f;
      float a1 = cval[nt] ? fminf(S[nt][1] + pt[myq[1] * 24 + okp[nt]], 86.f) : -1e30f;
      float a2 = cval[nt] ? fminf(S[nt][2] + pt[myq[2] * 24 + okp[nt]], 86.f) : -1e30f;
      float a3 = cval[nt] ? fminf(S[nt][3] + pt[myq[3] * 24 + okp[nt]], 86.f) : -1e30f;
      unsigned u01 = pk2bf(EXP2(a0), EXP2(a1));
      unsigned u23 = pk2bf(EXP2(a2), EXP2(a3));
      Ps[(prb + 0) * 72 + cidx] = (unsigned short)u01;
      Ps[(prb + 1) * 72 + cidx] = (unsigned short)(u01 >> 16);
      Ps[(prb + 2) * 72 + cidx] = (unsigned short)u23;
      Ps[(prb + 3) * 72 + cidx] = (unsigned short)(u23 >> 16);
    }
    // O += P V  — Ps rows are wave-local: no barrier
    bf16x8 pa0 = *(const bf16x8*)&Ps[(wave * 16 + l15) * 72 + quad * 8];
    bf16x8 pa1 = *(const bf16x8*)&Ps[(wave * 16 + l15) * 72 + 32 + quad * 8];
#pragma unroll
    for (int nt = 0; nt < 5; nt++) {
      bf16x8 vb0 = *(const bf16x8*)&Vs[(nt * 16 + l15) * 88 + quad * 8];
      bf16x8 vb1 = *(const bf16x8*)&Vs[(nt * 16 + l15) * 88 + 32 + quad * 8];
      O[nt] = __builtin_amdgcn_mfma_f32_16x16x32_bf16(pa0, vb0, O[nt], 0, 0, 0);
      O[nt] = __builtin_amdgcn_mfma_f32_16x16x32_bf16(pa1, vb1, O[nt], 0, 0, 0);
    }
  }
#pragma unroll
  for (int r = 0; r < 4; r++) {
    int orow = q0 + wave * 16 + quad * 4 + r;         // < TK (64-row tiles)
    size_t base = ((size_t)(z * NHEAD + h) * TK + orow);
    if (l15 == 0) lbuf[base] = O[4][r];
#pragma unroll
    for (int nt = 0; nt < 4; nt++)
      Opart[base * 64 + nt * 16 + l15] = f2bf(O[nt][r]);
  }
}

// ---------------- merge flash splits (pure sum; m==0) -> ob (bf16 [T][512]) ---------

__global__ __launch_bounds__(256) void flash_merge(
    const unsigned short* __restrict__ Opart, const float* __restrict__ lbuf,
    unsigned short* __restrict__ ob)
{
  int idx = blockIdx.x * 256 + threadIdx.x;
  if (idx >= T_TOK * HIDDEN) return;
  int row = idx >> 9, c = idx & 511;
  int h = c >> 6, d = c & 63;
  float num = 0.f, den = 0.f;
#pragma unroll
  for (int s = 0; s < FSPLIT; s++) {
    size_t base = ((size_t)(s * NHEAD + h) * TK + row);
    den += lbuf[base];
    num += bf2f(Opart[base * 64 + d]);
  }
  ob[idx] = f2bf(num / den);
}

// ---------------- residual + bias + 4-way split-K sum + LN, fp32 + bf16 mirror -------

__global__ __launch_bounds__(256) void ln_residual4(
    float* __restrict__ x, const float* __restrict__ parts,
    const float* __restrict__ bias,
    const float* __restrict__ g, const float* __restrict__ b,
    unsigned short* __restrict__ xb)
{
  __shared__ float sb[4];
  int row = blockIdx.x;
  int j0 = threadIdx.x, j1 = threadIdx.x + 256;
  int base = row * HIDDEN;
  const size_t ss = (size_t)TP * HIDDEN;
  float v0 = x[base + j0] + bias[j0] + parts[base + j0] + parts[ss + base + j0]
           + parts[2 * ss + base + j0] + parts[3 * ss + base + j0];
  float v1 = x[base + j1] + bias[j1] + parts[base + j1] + parts[ss + base + j1]
           + parts[2 * ss + base + j1] + parts[3 * ss + base + j1];
  float s1 = blockReduceSum(v0 + v1, sb);
  float s2 = blockReduceSum(v0 * v0 + v1 * v1, sb);
  float m = s1 * (1.0f / HIDDEN);
  float var = s2 * (1.0f / HIDDEN) - m * m;
  float inv = rsqrtf(var + 1e-5f);
  float y0 = (v0 - m) * inv * g[j0] + b[j0];
  float y1 = (v1 - m) * inv * g[j1] + b[j1];
  x[base + j0] = y0;
  x[base + j1] = y1;
  xb[base + j0] = f2bf(y0);
  xb[base + j1] = f2bf(y1);
}

__global__ __launch_bounds__(256) void copy_out(
    const float4* __restrict__ src, float4* __restrict__ dst, int n4)
{
  int i = blockIdx.x * 256 + threadIdx.x;
  if (i < n4) dst[i] = src[i];
}

// ---------------- driver ----------------

extern "C" void kernel_launch(void* const* d_in, const int* in_sizes, int n_in,
                              void* d_out, int out_size, void* d_ws, size_t ws_size,
                              hipStream_t stream) {
  const float* obj   = (const float*)d_in[0];
  const float* st0   = (const float*)d_in[2];
  const int*   rpe_a = (const int*)d_in[3];
  const int*   rpe_d = (const int*)d_in[4];
  const float* mask  = (const float*)d_in[5];
  const float* Wpg = (const float*)d_in[6];  const float* bpg = (const float*)d_in[7];
  const float* pg_g = (const float*)d_in[8]; const float* pg_b = (const float*)d_in[9];
  const float* Wps = (const float*)d_in[10]; const float* bps = (const float*)d_in[11];
  const float* ps_g = (const float*)d_in[12];const float* ps_b = (const float*)d_in[13];
  const float* emb_a = (const float*)d_in[14];
  const float* emb_d = (const float*)d_in[15];
  const float* Wq = (const float*)d_in[16]; const float* bq = (const float*)d_in[17];
  const float* Wk = (const float*)d_in[18]; const float* bk = (const float*)d_in[19];
  const float* Wv = (const float*)d_in[20]; const float* bv = (const float*)d_in[21];
  const float* Wo = (const float*)d_in[22]; const float* bo = (const float*)d_in[23];
  const float* W1 = (const float*)d_in[24]; const float* b1 = (const float*)d_in[25];
  const float* W2 = (const float*)d_in[26]; const float* b2 = (const float*)d_in[27];
  const float* ln1_g = (const float*)d_in[28]; const float* ln1_b = (const float*)d_in[29];
  const float* ln2_g = (const float*)d_in[30]; const float* ln2_b = (const float*)d_in[31];

  // ---- workspace layout ----
  char* p = (char*)d_ws;
  auto alloc = [&](size_t bytes) { char* q = p; p += (bytes + 255) & ~(size_t)255; return q; };
  float*          x      = (float*)alloc((size_t)T_TOK * HIDDEN * 4);
  unsigned short* xb     = (unsigned short*)alloc((size_t)TP * HIDDEN * 2);
  // union1: {qhb,khb,vhb,vtb} (attention phase) | hb (FFN phase)
  char*           u1     = (char*)alloc((size_t)TP * FFDIM * 2);
  unsigned short* qhb    = (unsigned short*)u1;
  unsigned short* khb    = qhb + (size_t)NHEAD * TP * ADIM;
  unsigned short* vhb    = khb + (size_t)NHEAD * TP * ADIM;
  unsigned short* vtb    = vhb + (size_t)NHEAD * TP * ADIM;
  unsigned short* hb     = (unsigned short*)u1;
  unsigned short* ob     = (unsigned short*)alloc((size_t)TP * HIDDEN * 2);
  // union2: {Opart(bf16)+lbuf} (flash) | parts (split-K GEMM fp32)
  size_t opartB = (size_t)FSPLIT * NHEAD * TK * ADIM * 2;
  size_t partsB = (size_t)NSPLIT * TP * HIDDEN * 4;
  size_t u2B = opartB + (size_t)FSPLIT * NHEAD * TK * 4;
  if (partsB > u2B) u2B = partsB;
  char*           u2     = (char*)alloc(u2B);
  unsigned short* Opart  = (unsigned short*)u2;
  float*          lbb    = (float*)(u2 + opartB);
  float*          parts  = (float*)u2;
  unsigned short* posb   = (unsigned short*)alloc((size_t)NHEAD * NORIG * NORIG * 2);
  size_t perLayerW = ((size_t)1536 * 512 + 512 * 512 + 2048 * 512 + 512 * 2048) * 2;
  size_t baseUsed = (size_t)(p - (char*)d_ws);
  bool hoist = (baseUsed + 6 * perLayerW + 2048) <= ws_size;
  int nWsets = hoist ? 6 : 1;
  unsigned short* Wsets = (unsigned short*)alloc(perLayerW * nWsets);
  if ((size_t)(p - (char*)d_ws) > ws_size) return;

  auto wq_t = [&](int l) { return Wsets + (hoist ? l : 0) * (perLayerW / 2); };
  auto wo_t = [&](int l) { return wq_t(l) + (size_t)1536 * 512; };
  auto w1_t = [&](int l) { return wo_t(l) + (size_t)512 * 512; };
  auto w2_t = [&](int l) { return w1_t(l) + (size_t)2048 * 512; };

  float* out = (float*)d_out;

  embed_kernel<<<T_TOK, 256, 0, stream>>>(obj, st0, Wpg, bpg, pg_g, pg_b,
                                          Wps, bps, ps_g, ps_b, x, xb);
  padzero<<<((TP - T_TOK) * HIDDEN + 255) / 256, 256, 0, stream>>>(xb);
  posbuild<<<NORIG, 256, 0, stream>>>(rpe_a, rpe_d, emb_a, emb_d, mask, posb);
  if (hoist) {
    for (int l = 0; l < NLAYER; l++)
      wtrans<<<768, 256, 0, stream>>>(
          Wq + l * 512 * 512, Wk + l * 512 * 512, Wv + l * 512 * 512,
          Wo + l * 512 * 512, W1 + l * 512 * 2048, W2 + l * 2048 * 512,
          wq_t(l), wo_t(l), w1_t(l), w2_t(l));
  }

  for (int l = 0; l < NLAYER; l++) {
    if (!hoist) {
      wtrans<<<768, 256, 0, stream>>>(
          Wq + l * 512 * 512, Wk + l * 512 * 512, Wv + l * 512 * 512,
          Wo + l * 512 * 512, W1 + l * 512 * 2048, W2 + l * 2048 * 512,
          wq_t(l), wo_t(l), w1_t(l), w2_t(l));
    }
    // QKV (N=1536 packed)
    gemm_bt<<<dim3(12, 34, 1), 256, 0, stream>>>(
        xb, HIDDEN, wq_t(l), HIDDEN, HIDDEN, 0,
        bq + l * 512, bk + l * 512, bv + l * 512, qhb, khb, vhb, nullptr, 0);
    vt_trans<<<dim3(33, 8), 256, 0, stream>>>(vhb, vtb);
    flash_attn<<<dim3(33, 8, FSPLIT), 256, 0, stream>>>(
        qhb, khb, vtb, posb, Opart, lbb);
    flash_merge<<<(T_TOK * HIDDEN + 255) / 256, 256, 0, stream>>>(Opart, lbb, ob);
    // O projection: split-K(4) -> parts, reduce fused into LN
    gemm_bt<<<dim3(4, 34, NSPLIT), 256, 0, stream>>>(
        ob, HIDDEN, wo_t(l), HIDDEN, HIDDEN, 1,
        nullptr, nullptr, nullptr, nullptr, nullptr, nullptr, parts, HIDDEN);
    ln_residual4<<<T_TOK, 256, 0, stream>>>(x, parts, bo + l * 512,
                                            ln1_g + l * 512, ln1_b + l * 512, xb);
    // FFN1 -> hb (bf16, leaky)
    gemm_bt<<<dim3(16, 34, 1), 256, 0, stream>>>(
        xb, HIDDEN, w1_t(l), HIDDEN, HIDDEN, 2,
        b1 + l * 2048, nullptr, nullptr, hb, nullptr, nullptr, nullptr, FFDIM);
    // FFN2: split-K(4) -> parts
    gemm_bt<<<dim3(4, 34, NSPLIT), 256, 0, stream>>>(
        hb, FFDIM, w2_t(l), FFDIM, FFDIM, 1,
        nullptr, nullptr, nullptr, nullptr, nullptr, nullptr, parts, HIDDEN);
    ln_residual4<<<T_TOK, 256, 0, stream>>>(x, parts, b2 + l * 512,
                                            ln2_g + l * 512, ln2_b + l * 512, xb);
  }

  int n4 = T_TOK * HIDDEN / 4;
  copy_out<<<(n4 + 255) / 256, 256, 0, stream>>>((const float4*)x, (float4*)out, n4);
}

// Round 9
// 937.339 us; speedup vs baseline: 1.1562x; 1.0219x over previous
//
#include <hip/hip_runtime.h>
#include <math.h>

#define T_TOK 2056
#define TP 2176      // 17*128  M-padded rows
#define TK 2112      // 33*64   KV-padded rows
#define HIDDEN 512
#define NHEAD 8
#define ADIM 64
#define FFDIM 2048
#define NLAYER 6
#define NORIG 520
#define NOBJ 8
#define NSPLIT 4     // GEMM K-splits
#define FSPLIT 8     // flash KV splits

typedef float f32x4 __attribute__((ext_vector_type(4)));
typedef __attribute__((__ext_vector_type__(8))) __bf16 bf16x8;

#if __has_builtin(__builtin_amdgcn_exp2f)
#define EXP2(x) __builtin_amdgcn_exp2f(x)
#else
#define EXP2(x) exp2f(x)
#endif

__device__ __forceinline__ unsigned short f2bf(float f) {
  unsigned int u = __float_as_uint(f);
  u += 0x7FFFu + ((u >> 16) & 1u);
  return (unsigned short)(u >> 16);
}
__device__ __forceinline__ float bf2f(unsigned short u) {
  return __uint_as_float(((unsigned int)u) << 16);
}
// packed f32x2 -> bf16x2 (lo = a, hi = b); HW single-op on gfx950
__device__ __forceinline__ unsigned pk2bf(float a, float b) {
#if __has_builtin(__builtin_amdgcn_cvt_pk_bf16_f32)
  auto v = __builtin_amdgcn_cvt_pk_bf16_f32(a, b);
  unsigned u;
  __builtin_memcpy(&u, &v, 4);
  return u;
#else
  return (unsigned)f2bf(a) | ((unsigned)f2bf(b) << 16);
#endif
}

// async global -> LDS, 16 B per lane (global_load_lds_dwordx4)
__device__ __forceinline__ void gl_lds16(const void* g, void* l) {
  __builtin_amdgcn_global_load_lds(
      (const __attribute__((address_space(1))) void*)g,
      (__attribute__((address_space(3))) void*)l, 16, 0, 0);
}

// ---------------- block reduction helpers (256 threads = 4 waves) ----------------

__device__ inline float blockReduceSum(float v, float* sb) {
#pragma unroll
  for (int off = 32; off > 0; off >>= 1) v += __shfl_down(v, off, 64);
  int wid = threadIdx.x >> 6;
  __syncthreads();
  if ((threadIdx.x & 63) == 0) sb[wid] = v;
  __syncthreads();
  return sb[0] + sb[1] + sb[2] + sb[3];
}

// ---------------- token embedding: project + LN + leaky_relu (fp32 + bf16 mirror) ----
// grid = TP; pad rows (t >= T_TOK) just zero the bf16 mirror.

__global__ __launch_bounds__(256) void embed_kernel(
    const float* __restrict__ obj, const float* __restrict__ st0,
    const float* __restrict__ Wpg, const float* __restrict__ bpg,
    const float* __restrict__ pg_g, const float* __restrict__ pg_b,
    const float* __restrict__ Wps, const float* __restrict__ bps,
    const float* __restrict__ ps_g, const float* __restrict__ ps_b,
    float* __restrict__ x, unsigned short* __restrict__ xb)
{
  __shared__ float sb[4];
  int t = blockIdx.x;
  int j0 = threadIdx.x, j1 = threadIdx.x + 256;
  if (t >= T_TOK) {           // pad row: zero xb only (uniform per block)
    xb[t * HIDDEN + j0] = 0;
    xb[t * HIDDEN + j1] = 0;
    return;
  }
  float a0, a1;
  const float *g, *b;
  if (t < NOBJ) {
    a0 = bpg[j0]; a1 = bpg[j1];
    const float* in = obj + t * 100;
    for (int i = 0; i < 100; i++) {
      float w = in[i];
      a0 += w * Wpg[i * HIDDEN + j0];
      a1 += w * Wpg[i * HIDDEN + j1];
    }
    g = pg_g; b = pg_b;
  } else {
    int tt = t - NOBJ, s = tt >> 2, p = tt & 3;
    float c0 = st0[s * 10 + p * 2], c1 = st0[s * 10 + p * 2 + 1];
    a0 = bps[j0] + c0 * Wps[j0] + c1 * Wps[HIDDEN + j0];
    a1 = bps[j1] + c0 * Wps[j1] + c1 * Wps[HIDDEN + j1];
    g = ps_g; b = ps_b;
  }
  float s1 = blockReduceSum(a0 + a1, sb);
  float s2 = blockReduceSum(a0 * a0 + a1 * a1, sb);
  float m = s1 * (1.0f / HIDDEN);
  float var = s2 * (1.0f / HIDDEN) - m * m;
  float inv = rsqrtf(var + 1e-5f);
  float y0 = (a0 - m) * inv * g[j0] + b[j0];
  float y1 = (a1 - m) * inv * g[j1] + b[j1];
  y0 = y0 >= 0.f ? y0 : 0.01f * y0;
  y1 = y1 >= 0.f ? y1 : 0.01f * y1;
  x[t * HIDDEN + j0] = y0;
  x[t * HIDDEN + j1] = y1;
  xb[t * HIDDEN + j0] = f2bf(y0);
  xb[t * HIDDEN + j1] = f2bf(y1);
}

// ---------------- precompute rel-pos bias table: posb[h][520][520] (bf16) ----------
// posb = ((emb_a[rpe_a]+emb_d[rpe_d]) * 0.125 + mask) * log2(e)   (layer-invariant)

__global__ __launch_bounds__(256) void posbuild(
    const int* __restrict__ rpe_a, const int* __restrict__ rpe_d,
    const float* __restrict__ emb_a, const float* __restrict__ emb_d,
    const float* __restrict__ mask, unsigned short* __restrict__ posb)
{
  int i = blockIdx.x;
  for (int j = threadIdx.x; j < NORIG; j += 256) {
    int a = rpe_a[i * NORIG + j];
    int d = rpe_d[i * NORIG + j];
    float mk = mask[i * NORIG + j];
#pragma unroll
    for (int h = 0; h < NHEAD; h++) {
      float v = ((emb_a[a * NHEAD + h] + emb_d[d * NHEAD + h]) * 0.125f + mk) * 1.44269504f;
      posb[(h * NORIG + i) * NORIG + j] = f2bf(v);
    }
  }
}

// ---------------- weight transpose+convert: fp32 [K][N] -> bf16 [N][K] ----------------

__global__ __launch_bounds__(256) void wtrans(
    const float* __restrict__ Wq, const float* __restrict__ Wk, const float* __restrict__ Wv,
    const float* __restrict__ Wo, const float* __restrict__ W1, const float* __restrict__ W2,
    unsigned short* __restrict__ Wqkvt, unsigned short* __restrict__ Wot,
    unsigned short* __restrict__ W1t, unsigned short* __restrict__ W2t)
{
  __shared__ float t[64 * 65];
  int b = blockIdx.x;
  const float* src; unsigned short* dst; int N, K, tk, tn;
  if (b < 192) {
    int m = b >> 6, bb = b & 63;
    src = m == 0 ? Wq : m == 1 ? Wk : Wv;
    dst = Wqkvt + m * 512 * 512;
    K = 512; N = 512; tk = bb & 7; tn = bb >> 3;
  } else if (b < 256) {
    int bb = b - 192; src = Wo; dst = Wot; K = 512; N = 512; tk = bb & 7; tn = bb >> 3;
  } else if (b < 512) {
    int bb = b - 256; src = W1; dst = W1t; K = 512; N = 2048; tk = bb & 7; tn = bb >> 3;
  } else {
    int bb = b - 512; src = W2; dst = W2t; K = 2048; N = 512; tk = bb & 31; tn = bb >> 5;
  }
  int k0 = tk * 64, n0 = tn * 64;
  int tid = threadIdx.x;
  int r = tid >> 2, c0 = (tid & 3) * 16;
  const float* sp = src + (k0 + r) * N + n0 + c0;
#pragma unroll
  for (int q = 0; q < 4; q++) {
    float4 f = *(const float4*)(sp + q * 4);
    t[r * 65 + c0 + q * 4 + 0] = f.x;
    t[r * 65 + c0 + q * 4 + 1] = f.y;
    t[r * 65 + c0 + q * 4 + 2] = f.z;
    t[r * 65 + c0 + q * 4 + 3] = f.w;
  }
  __syncthreads();
  unsigned short vals[16];
#pragma unroll
  for (int j = 0; j < 16; j++) vals[j] = f2bf(t[(c0 + j) * 65 + r]);
  unsigned short* dp = dst + (n0 + r) * K + k0 + c0;
  *(int4*)dp = *(int4*)&vals[0];
  *(int4*)(dp + 8) = *(int4*)&vals[8];
}

// ---------------- MFMA GEMM: C[M=2176][N] = A[.][K] * Bt[N][K]^T, bf16 in / fp32 acc ----
// BM=64, BN=128, BK=64; 4 waves each 32x64; 16 MFMA per barrier (halved barrier count
// vs BK=32). Async global_load_lds staging (16B/lane), XOR swizzle over 8 slots/row:
// read spreads each bank across 8 lanes = LDS throughput minimum (conflict-free).
// mode 0: +bias(seg) -> Q/K scatter bf16 to qh/kh [head][TP][64]; V scatters DIRECTLY
//         to vt [head][64][TK] (vt_trans fused); Q scaled 0.125*log2e
// mode 1: split-K partial -> fp32 df[z][TP][ldc] (NO bias)
// mode 2: +bias, leaky -> bf16 d0

__global__ __launch_bounds__(256) void gemm_bt(
    const unsigned short* __restrict__ A, int lda,
    const unsigned short* __restrict__ Bt, int ldb, int K, int mode,
    const float* __restrict__ b0, const float* __restrict__ b1, const float* __restrict__ b2,
    unsigned short* __restrict__ d0, unsigned short* __restrict__ d1, unsigned short* __restrict__ d2,
    float* __restrict__ df, int ldc)
{
  __shared__ unsigned short As[2][64 * 64];
  __shared__ unsigned short Bs[2][128 * 64];
  const int tid = threadIdx.x;
  const int lane = tid & 63, wave = tid >> 6;
  const int l15 = lane & 15, quad = lane >> 4;
  const int rowBase = blockIdx.y * 64, colBase = blockIdx.x * 128;
  const int mw = (wave & 1) * 32, nw = (wave >> 1) * 64;
  const int zz = blockIdx.z;
  const int kLen = K / gridDim.z;
  const int kb0 = zz * kLen;
  const int nIter = kLen >> 6;           // >= 2 for all our shapes
  // --- staging geometry: slot s (16B) -> row = s>>3, lds slot (s&7) holds global
  // k-chunk (s&7)^(row&7). Thread tid stages A slots {tid, tid+256}, B slots
  // {tid, tid+256, tid+512, tid+768}.
  const int as0 = tid, as1 = tid + 256;
  const int ar0 = as0 >> 3, ar1 = as1 >> 3;
  const unsigned short* Ag0 = A + (size_t)(rowBase + ar0) * lda + kb0 + (((as0 & 7) ^ (ar0 & 7)) * 8);
  const unsigned short* Ag1 = A + (size_t)(rowBase + ar1) * lda + kb0 + (((as1 & 7) ^ (ar1 & 7)) * 8);
  const unsigned short* Bg[4];
#pragma unroll
  for (int j = 0; j < 4; j++) {
    int s = tid + 256 * j;
    int r = s >> 3;
    Bg[j] = Bt + (size_t)(colBase + r) * ldb + kb0 + (((s & 7) ^ (r & 7)) * 8);
  }
  // --- read-side swizzled offsets (elements), per k-half
  int aoff[2][2], boff[4][2];
#pragma unroll
  for (int mt = 0; mt < 2; mt++) {
    int row = mw + mt * 16 + l15;
#pragma unroll
    for (int kh = 0; kh < 2; kh++)
      aoff[mt][kh] = row * 64 + (((quad + kh * 4) ^ (row & 7)) * 8);
  }
#pragma unroll
  for (int nt = 0; nt < 4; nt++) {
    int row = nw + nt * 16 + l15;
#pragma unroll
    for (int kh = 0; kh < 2; kh++)
      boff[nt][kh] = row * 64 + (((quad + kh * 4) ^ (row & 7)) * 8);
  }
  f32x4 acc[2][4];
#pragma unroll
  for (int i = 0; i < 2; i++)
#pragma unroll
    for (int j = 0; j < 4; j++) acc[i][j] = (f32x4){0.f, 0.f, 0.f, 0.f};

  // issue iter-0 loads into buf0 (async)
  gl_lds16(Ag0, (unsigned short*)As[0] + as0 * 8);
  gl_lds16(Ag1, (unsigned short*)As[0] + as1 * 8);
#pragma unroll
  for (int j = 0; j < 4; j++)
    gl_lds16(Bg[j], (unsigned short*)Bs[0] + (tid + 256 * j) * 8);

  for (int it = 0; it < nIter; ++it) {
    const int cur = it & 1, nxt = cur ^ 1;
    __syncthreads();   // drains outstanding global_load_lds (vmcnt0) + barrier
    if (it + 1 < nIter) {
      int koff = (it + 1) * 64;
      gl_lds16(Ag0 + koff, (unsigned short*)As[nxt] + as0 * 8);
      gl_lds16(Ag1 + koff, (unsigned short*)As[nxt] + as1 * 8);
#pragma unroll
      for (int j = 0; j < 4; j++)
        gl_lds16(Bg[j] + koff, (unsigned short*)Bs[nxt] + (tid + 256 * j) * 8);
    }
#pragma unroll
    for (int kh = 0; kh < 2; kh++) {
      bf16x8 af[2], bfr[4];
#pragma unroll
      for (int mt = 0; mt < 2; mt++)
        af[mt] = *(const bf16x8*)&As[cur][aoff[mt][kh]];
#pragma unroll
      for (int nt = 0; nt < 4; nt++)
        bfr[nt] = *(const bf16x8*)&Bs[cur][boff[nt][kh]];
#pragma unroll
      for (int mt = 0; mt < 2; mt++)
#pragma unroll
        for (int nt = 0; nt < 4; nt++)
          acc[mt][nt] = __builtin_amdgcn_mfma_f32_16x16x32_bf16(af[mt], bfr[nt], acc[mt][nt], 0, 0, 0);
    }
  }

  float* dfz = df + (size_t)zz * TP * ldc;
#pragma unroll
  for (int mt = 0; mt < 2; mt++) {
#pragma unroll
    for (int nt = 0; nt < 4; nt++) {
#pragma unroll
      for (int r = 0; r < 4; r++) {
        int row = rowBase + mw + mt * 16 + quad * 4 + r;
        int col = colBase + nw + nt * 16 + l15;
        float v = acc[mt][nt][r];
        if (mode == 0) {
          int seg = col >> 9, cc = col & 511;
          const float* bs = seg == 0 ? b0 : seg == 1 ? b1 : b2;
          int hd = cc >> 6, d = cc & 63;
          float t = v + bs[cc];
          if (seg == 0) {
            t *= 0.180336880111f;  // 0.125 * log2(e) folded into Q
            d0[(hd * TP + row) * 64 + d] = f2bf(t);
          } else if (seg == 1) {
            d1[(hd * TP + row) * 64 + d] = f2bf(t);
          } else {
            // V: scatter transposed straight into vt [h][64][TK]
            if (row < TK) d2[(hd * 64 + d) * TK + row] = f2bf(t);
          }
        } else if (mode == 1) {
          dfz[row * ldc + col] = v;
        } else {
          float t = v + b0[col];
          t = t >= 0.f ? t : 0.01f * t;
          d0[row * ldc + col] = f2bf(t);
        }
      }
    }
  }
}

// ---------------- split-KV flash attention, shift-free exp2 softmax, pipelined -------
// (round-5/8 configuration: 64-row q-tiles, FSPLIT=8 — highest measured occupancy)
// grid (33 q-tiles, 8 heads, FSPLIT); split z handles tiles kt = z, z+FSPLIT, ...
// Next tile's K/V/pos prefetched into regs during current tile's compute.
// Ps write->read is wave-local: no barrier between epilogue and PV.
// Row-sum l via ones-column 5th V n-tile (O[4]). Opart bf16; m == 0 implied.

__global__ __launch_bounds__(256) void flash_attn(
    const unsigned short* __restrict__ qh, const unsigned short* __restrict__ kh,
    const unsigned short* __restrict__ vt, const unsigned short* __restrict__ posb,
    unsigned short* __restrict__ Opart, float* __restrict__ lbuf)
{
  __shared__ unsigned short Ks[64 * 72];
  __shared__ unsigned short Vs[80 * 88];   // rows 0-63: V^T; rows 64-79: ones-col tile
  __shared__ unsigned short Ps[64 * 72];
  __shared__ float pt[24 * 24];
  const int tid = threadIdx.x;
  const int lane = tid & 63, wave = tid >> 6;
  const int l15 = lane & 15, quad = lane >> 4;
  const int qt = blockIdx.x, h = blockIdx.y, z = blockIdx.z;
  const int q0 = qt * 64;
  const int qrow = q0 + wave * 16 + l15;
  const unsigned short* qbp = qh + (h * TP + qrow) * 64;
  bf16x8 qf0 = *(const bf16x8*)(qbp + quad * 8);
  bf16x8 qf1 = *(const bf16x8*)(qbp + 32 + quad * 8);
  f32x4 O[5];
#pragma unroll
  for (int nt = 0; nt < 5; nt++) O[nt] = (f32x4){0.f, 0.f, 0.f, 0.f};
  for (int idx = tid; idx < 16 * 88; idx += 256) {
    int rr = idx / 88, cc = idx - rr * 88;
    Vs[(64 + rr) * 88 + cc] = (rr == 0) ? 0x3F80 : 0;
  }
  const int oq0 = q0 < 8 ? q0 : 8 + ((q0 - 8) >> 2);
  const int qe = min(q0 + 63, T_TOK - 1);
  const int nq = (qe < 8 ? qe : 8 + ((qe - 8) >> 2)) - oq0 + 1;
  int myq[4];
#pragma unroll
  for (int r = 0; r < 4; r++) {
    int qr = q0 + wave * 16 + quad * 4 + r;
    myq[r] = (qr < 8 ? qr : 8 + ((qr - 8) >> 2)) - oq0;
  }
  const int sr = tid >> 3, sc = (tid & 7) * 8;
  const unsigned short* kgb = kh + (h * TP + sr) * 64 + sc;
  const unsigned short* vgb = vt + (h * 64 + sr) * TK + sc;
  const int ptrow = tid >> 3, ptc0 = (tid & 7) * 3;
  const bool prok = (ptrow < 24) && (ptrow < nq);

  const int nT = (33 - z + FSPLIT - 1) / FSPLIT;
  int kb = z * 64;
  // prefetch tile 0
  int4 kv0 = *(const int4*)(kgb + kb * 64);
  int4 kv1 = *(const int4*)(kgb + (kb + 32) * 64);
  int4 vv0 = *(const int4*)(vgb + kb);
  int4 vv1 = *(const int4*)(vgb + 32 * TK + kb);
  float ppf0, ppf1, ppf2;
  {
    int ok0n = kb < 8 ? kb : 8 + ((kb - 8) >> 2);
    int ken = min(kb + 63, T_TOK - 1);
    int nkn = (ken < 8 ? ken : 8 + ((ken - 8) >> 2)) - ok0n + 1;
    const unsigned short* prow = posb + (h * NORIG + oq0 + ptrow) * NORIG + ok0n;
    ppf0 = (prok && ptc0 + 0 < nkn) ? bf2f(prow[ptc0 + 0]) : 0.f;
    ppf1 = (prok && ptc0 + 1 < nkn) ? bf2f(prow[ptc0 + 1]) : 0.f;
    ppf2 = (prok && ptc0 + 2 < nkn) ? bf2f(prow[ptc0 + 2]) : 0.f;
  }

  for (int it = 0; it < nT; ++it) {
    const int kbCur = kb;
    const int ok0c = kbCur < 8 ? kbCur : 8 + ((kbCur - 8) >> 2);
    __syncthreads();                       // prev tile's LDS reads complete
    *(int4*)&Ks[sr * 72 + sc] = kv0;
    *(int4*)&Ks[(sr + 32) * 72 + sc] = kv1;
    *(int4*)&Vs[sr * 88 + sc] = vv0;
    *(int4*)&Vs[(sr + 32) * 88 + sc] = vv1;
    if (ptrow < 24) {
      pt[ptrow * 24 + ptc0 + 0] = ppf0;
      pt[ptrow * 24 + ptc0 + 1] = ppf1;
      pt[ptrow * 24 + ptc0 + 2] = ppf2;
    }
    __syncthreads();
    kb += FSPLIT * 64;
    if (it + 1 < nT) {                     // prefetch next tile during compute
      kv0 = *(const int4*)(kgb + kb * 64);
      kv1 = *(const int4*)(kgb + (kb + 32) * 64);
      vv0 = *(const int4*)(vgb + kb);
      vv1 = *(const int4*)(vgb + 32 * TK + kb);
      int ok0n = kb < 8 ? kb : 8 + ((kb - 8) >> 2);
      int ken = min(kb + 63, T_TOK - 1);
      int nkn = (ken < 8 ? ken : 8 + ((ken - 8) >> 2)) - ok0n + 1;
      const unsigned short* prow = posb + (h * NORIG + oq0 + ptrow) * NORIG + ok0n;
      ppf0 = (prok && ptc0 + 0 < nkn) ? bf2f(prow[ptc0 + 0]) : 0.f;
      ppf1 = (prok && ptc0 + 1 < nkn) ? bf2f(prow[ptc0 + 1]) : 0.f;
      ppf2 = (prok && ptc0 + 2 < nkn) ? bf2f(prow[ptc0 + 2]) : 0.f;
    }
    // S = Q K^T
    f32x4 S[4];
#pragma unroll
    for (int nt = 0; nt < 4; nt++) S[nt] = (f32x4){0.f, 0.f, 0.f, 0.f};
#pragma unroll
    for (int nt = 0; nt < 4; nt++) {
      bf16x8 kf0 = *(const bf16x8*)&Ks[(nt * 16 + l15) * 72 + quad * 8];
      bf16x8 kf1 = *(const bf16x8*)&Ks[(nt * 16 + l15) * 72 + 32 + quad * 8];
      S[nt] = __builtin_amdgcn_mfma_f32_16x16x32_bf16(qf0, kf0, S[nt], 0, 0, 0);
      S[nt] = __builtin_amdgcn_mfma_f32_16x16x32_bf16(qf1, kf1, S[nt], 0, 0, 0);
    }
    int okp[4]; bool cval[4];
#pragma unroll
    for (int nt = 0; nt < 4; nt++) {
      int c = kbCur + nt * 16 + l15;
      cval[nt] = c < T_TOK;
      okp[nt] = (c < 8 ? c : 8 + ((c - 8) >> 2)) - ok0c;
    }
    const int prb = wave * 16 + quad * 4;
#pragma unroll
    for (int nt = 0; nt < 4; nt++) {
      const int cidx = nt * 16 + l15;
      float a0 = cval[nt] ? fminf(S[nt][0] + pt[myq[0] * 24 + okp[nt]], 86.f) : -1e30f;
      float a1 = cval[nt] ? fminf(S[nt][1] + pt[myq[1] * 24 + okp[nt]], 86.f) : -1e30f;
      float a2 = cval[nt] ? fminf(S[nt][2] + pt[myq[2] * 24 + okp[nt]], 86.f) : -1e30f;
      float a3 = cval[nt] ? fminf(S[nt][3] + pt[myq[3] * 24 + okp[nt]], 86.f) : -1e30f;
      unsigned u01 = pk2bf(EXP2(a0), EXP2(a1));
      unsigned u23 = pk2bf(EXP2(a2), EXP2(a3));
      Ps[(prb + 0) * 72 + cidx] = (unsigned short)u01;
      Ps[(prb + 1) * 72 + cidx] = (unsigned short)(u01 >> 16);
      Ps[(prb + 2) * 72 + cidx] = (unsigned short)u23;
      Ps[(prb + 3) * 72 + cidx] = (unsigned short)(u23 >> 16);
    }
    // O += P V  — Ps rows are wave-local: no barrier
    bf16x8 pa0 = *(const bf16x8*)&Ps[(wave * 16 + l15) * 72 + quad * 8];
    bf16x8 pa1 = *(const bf16x8*)&Ps[(wave * 16 + l15) * 72 + 32 + quad * 8];
#pragma unroll
    for (int nt = 0; nt < 5; nt++) {
      bf16x8 vb0 = *(const bf16x8*)&Vs[(nt * 16 + l15) * 88 + quad * 8];
      bf16x8 vb1 = *(const bf16x8*)&Vs[(nt * 16 + l15) * 88 + 32 + quad * 8];
      O[nt] = __builtin_amdgcn_mfma_f32_16x16x32_bf16(pa0, vb0, O[nt], 0, 0, 0);
      O[nt] = __builtin_amdgcn_mfma_f32_16x16x32_bf16(pa1, vb1, O[nt], 0, 0, 0);
    }
  }
#pragma unroll
  for (int r = 0; r < 4; r++) {
    int orow = q0 + wave * 16 + quad * 4 + r;         // < TK (64-row tiles)
    size_t base = ((size_t)(z * NHEAD + h) * TK + orow);
    if (l15 == 0) lbuf[base] = O[4][r];
#pragma unroll
    for (int nt = 0; nt < 4; nt++)
      Opart[base * 64 + nt * 16 + l15] = f2bf(O[nt][r]);
  }
}

// ---------------- merge flash splits (pure sum; m==0) -> ob (bf16 [T][512]) ---------

__global__ __launch_bounds__(256) void flash_merge(
    const unsigned short* __restrict__ Opart, const float* __restrict__ lbuf,
    unsigned short* __restrict__ ob)
{
  int idx = blockIdx.x * 256 + threadIdx.x;
  if (idx >= T_TOK * HIDDEN) return;
  int row = idx >> 9, c = idx & 511;
  int h = c >> 6, d = c & 63;
  float num = 0.f, den = 0.f;
#pragma unroll
  for (int s = 0; s < FSPLIT; s++) {
    size_t base = ((size_t)(s * NHEAD + h) * TK + row);
    den += lbuf[base];
    num += bf2f(Opart[base * 64 + d]);
  }
  ob[idx] = f2bf(num / den);
}

// ---------------- residual + bias + 4-way split-K sum + LN, fp32 + bf16 mirror -------

__global__ __launch_bounds__(256) void ln_residual4(
    float* __restrict__ x, const float* __restrict__ parts,
    const float* __restrict__ bias,
    const float* __restrict__ g, const float* __restrict__ b,
    unsigned short* __restrict__ xb)
{
  __shared__ float sb[4];
  int row = blockIdx.x;
  int j0 = threadIdx.x, j1 = threadIdx.x + 256;
  int base = row * HIDDEN;
  const size_t ss = (size_t)TP * HIDDEN;
  float v0 = x[base + j0] + bias[j0] + parts[base + j0] + parts[ss + base + j0]
           + parts[2 * ss + base + j0] + parts[3 * ss + base + j0];
  float v1 = x[base + j1] + bias[j1] + parts[base + j1] + parts[ss + base + j1]
           + parts[2 * ss + base + j1] + parts[3 * ss + base + j1];
  float s1 = blockReduceSum(v0 + v1, sb);
  float s2 = blockReduceSum(v0 * v0 + v1 * v1, sb);
  float m = s1 * (1.0f / HIDDEN);
  float var = s2 * (1.0f / HIDDEN) - m * m;
  float inv = rsqrtf(var + 1e-5f);
  float y0 = (v0 - m) * inv * g[j0] + b[j0];
  float y1 = (v1 - m) * inv * g[j1] + b[j1];
  x[base + j0] = y0;
  x[base + j1] = y1;
  xb[base + j0] = f2bf(y0);
  xb[base + j1] = f2bf(y1);
}

__global__ __launch_bounds__(256) void copy_out(
    const float4* __restrict__ src, float4* __restrict__ dst, int n4)
{
  int i = blockIdx.x * 256 + threadIdx.x;
  if (i < n4) dst[i] = src[i];
}

// ---------------- driver ----------------

extern "C" void kernel_launch(void* const* d_in, const int* in_sizes, int n_in,
                              void* d_out, int out_size, void* d_ws, size_t ws_size,
                              hipStream_t stream) {
  const float* obj   = (const float*)d_in[0];
  const float* st0   = (const float*)d_in[2];
  const int*   rpe_a = (const int*)d_in[3];
  const int*   rpe_d = (const int*)d_in[4];
  const float* mask  = (const float*)d_in[5];
  const float* Wpg = (const float*)d_in[6];  const float* bpg = (const float*)d_in[7];
  const float* pg_g = (const float*)d_in[8]; const float* pg_b = (const float*)d_in[9];
  const float* Wps = (const float*)d_in[10]; const float* bps = (const float*)d_in[11];
  const float* ps_g = (const float*)d_in[12];const float* ps_b = (const float*)d_in[13];
  const float* emb_a = (const float*)d_in[14];
  const float* emb_d = (const float*)d_in[15];
  const float* Wq = (const float*)d_in[16]; const float* bq = (const float*)d_in[17];
  const float* Wk = (const float*)d_in[18]; const float* bk = (const float*)d_in[19];
  const float* Wv = (const float*)d_in[20]; const float* bv = (const float*)d_in[21];
  const float* Wo = (const float*)d_in[22]; const float* bo = (const float*)d_in[23];
  const float* W1 = (const float*)d_in[24]; const float* b1 = (const float*)d_in[25];
  const float* W2 = (const float*)d_in[26]; const float* b2 = (const float*)d_in[27];
  const float* ln1_g = (const float*)d_in[28]; const float* ln1_b = (const float*)d_in[29];
  const float* ln2_g = (const float*)d_in[30]; const float* ln2_b = (const float*)d_in[31];

  // ---- workspace layout ----
  char* p = (char*)d_ws;
  auto alloc = [&](size_t bytes) { char* q = p; p += (bytes + 255) & ~(size_t)255; return q; };
  float*          x      = (float*)alloc((size_t)T_TOK * HIDDEN * 4);
  unsigned short* xb     = (unsigned short*)alloc((size_t)TP * HIDDEN * 2);
  // union1: {qhb,khb,vtb} (attention phase) | hb (FFN phase)
  char*           u1     = (char*)alloc((size_t)TP * FFDIM * 2);
  unsigned short* qhb    = (unsigned short*)u1;
  unsigned short* khb    = qhb + (size_t)NHEAD * TP * ADIM;
  unsigned short* vtb    = khb + (size_t)NHEAD * TP * ADIM;   // [h][64][TK]
  unsigned short* hb     = (unsigned short*)u1;
  unsigned short* ob     = (unsigned short*)alloc((size_t)TP * HIDDEN * 2);
  // union2: {Opart(bf16)+lbuf} (flash) | parts (split-K GEMM fp32)
  size_t opartB = (size_t)FSPLIT * NHEAD * TK * ADIM * 2;
  size_t partsB = (size_t)NSPLIT * TP * HIDDEN * 4;
  size_t u2B = opartB + (size_t)FSPLIT * NHEAD * TK * 4;
  if (partsB > u2B) u2B = partsB;
  char*           u2     = (char*)alloc(u2B);
  unsigned short* Opart  = (unsigned short*)u2;
  float*          lbb    = (float*)(u2 + opartB);
  float*          parts  = (float*)u2;
  unsigned short* posb   = (unsigned short*)alloc((size_t)NHEAD * NORIG * NORIG * 2);
  size_t perLayerW = ((size_t)1536 * 512 + 512 * 512 + 2048 * 512 + 512 * 2048) * 2;
  size_t baseUsed = (size_t)(p - (char*)d_ws);
  bool hoist = (baseUsed + 6 * perLayerW + 2048) <= ws_size;
  int nWsets = hoist ? 6 : 1;
  unsigned short* Wsets = (unsigned short*)alloc(perLayerW * nWsets);
  if ((size_t)(p - (char*)d_ws) > ws_size) return;

  auto wq_t = [&](int l) { return Wsets + (hoist ? l : 0) * (perLayerW / 2); };
  auto wo_t = [&](int l) { return wq_t(l) + (size_t)1536 * 512; };
  auto w1_t = [&](int l) { return wo_t(l) + (size_t)512 * 512; };
  auto w2_t = [&](int l) { return w1_t(l) + (size_t)2048 * 512; };

  float* out = (float*)d_out;

  embed_kernel<<<TP, 256, 0, stream>>>(obj, st0, Wpg, bpg, pg_g, pg_b,
                                       Wps, bps, ps_g, ps_b, x, xb);
  posbuild<<<NORIG, 256, 0, stream>>>(rpe_a, rpe_d, emb_a, emb_d, mask, posb);
  if (hoist) {
    for (int l = 0; l < NLAYER; l++)
      wtrans<<<768, 256, 0, stream>>>(
          Wq + l * 512 * 512, Wk + l * 512 * 512, Wv + l * 512 * 512,
          Wo + l * 512 * 512, W1 + l * 512 * 2048, W2 + l * 2048 * 512,
          wq_t(l), wo_t(l), w1_t(l), w2_t(l));
  }

  for (int l = 0; l < NLAYER; l++) {
    if (!hoist) {
      wtrans<<<768, 256, 0, stream>>>(
          Wq + l * 512 * 512, Wk + l * 512 * 512, Wv + l * 512 * 512,
          Wo + l * 512 * 512, W1 + l * 512 * 2048, W2 + l * 2048 * 512,
          wq_t(l), wo_t(l), w1_t(l), w2_t(l));
    }
    // QKV (N=1536 packed); V scatters directly into vtb (vt_trans fused)
    gemm_bt<<<dim3(12, 34, 1), 256, 0, stream>>>(
        xb, HIDDEN, wq_t(l), HIDDEN, HIDDEN, 0,
        bq + l * 512, bk + l * 512, bv + l * 512, qhb, khb, vtb, nullptr, 0);
    flash_attn<<<dim3(33, 8, FSPLIT), 256, 0, stream>>>(
        qhb, khb, vtb, posb, Opart, lbb);
    flash_merge<<<(T_TOK * HIDDEN + 255) / 256, 256, 0, stream>>>(Opart, lbb, ob);
    // O projection: split-K(4) -> parts, reduce fused into LN
    gemm_bt<<<dim3(4, 34, NSPLIT), 256, 0, stream>>>(
        ob, HIDDEN, wo_t(l), HIDDEN, HIDDEN, 1,
        nullptr, nullptr, nullptr, nullptr, nullptr, nullptr, parts, HIDDEN);
    ln_residual4<<<T_TOK, 256, 0, stream>>>(x, parts, bo + l * 512,
                                            ln1_g + l * 512, ln1_b + l * 512, xb);
    // FFN1 -> hb (bf16, leaky)
    gemm_bt<<<dim3(16, 34, 1), 256, 0, stream>>>(
        xb, HIDDEN, w1_t(l), HIDDEN, HIDDEN, 2,
        b1 + l * 2048, nullptr, nullptr, hb, nullptr, nullptr, nullptr, FFDIM);
    // FFN2: split-K(4) -> parts
    gemm_bt<<<dim3(4, 34, NSPLIT), 256, 0, stream>>>(
        hb, FFDIM, w2_t(l), FFDIM, FFDIM, 1,
        nullptr, nullptr, nullptr, nullptr, nullptr, nullptr, parts, HIDDEN);
    ln_residual4<<<T_TOK, 256, 0, stream>>>(x, parts, b2 + l * 512,
                                            ln2_g + l * 512, ln2_b + l * 512, xb);
  }

  int n4 = T_TOK * HIDDEN / 4;
  copy_out<<<(n4 + 255) / 256, 256, 0, stream>>>((const float4*)x, (float4*)out, n4);
}